// Round 9
// baseline (4999.773 us; speedup 1.0000x reference)
//
#include <hip/hip_runtime.h>
#include <hip/hip_bf16.h>

#define BB 16
#define SS 512
#define VOCAB 32000
#define EMB 512
#define HID 1024
#define LAT 256
#define SENT 0x7FC07FC0u   // qNaN|qNaN packed bf16 pair — unreachable from tanh outputs

typedef __attribute__((ext_vector_type(8))) short bf16x8v;
typedef __attribute__((ext_vector_type(4))) float f32x4v;
typedef __attribute__((ext_vector_type(4))) unsigned int u32x4v;
typedef __attribute__((ext_vector_type(2))) unsigned long long u64x2v;
typedef unsigned long long u64;

__device__ __forceinline__ unsigned short f2b(float f) {
  unsigned int u = __float_as_uint(f);
  unsigned int r = (u + 0x7fffu + ((u >> 16) & 1u)) >> 16;
  return (unsigned short)r;
}

__device__ __forceinline__ float b2f(unsigned short s) {
  return __uint_as_float(((unsigned int)s) << 16);
}

__device__ __forceinline__ float fast_tanh(float x) {
  float t = fminf(fmaxf(x * 2.8853900817779268f, -60.f), 60.f);
  float e = __builtin_amdgcn_exp2f(t);
  return (e - 1.f) * __builtin_amdgcn_rcpf(e + 1.f);
}

// compiler-visible coherent 8B load (relaxed, agent scope): observes cross-XCD
// write-through stores (same mechanism as every flag poll since round 3), and
// the COMPILER manages s_waitcnt + spills — no inline-asm register hazards.
__device__ __forceinline__ u64 aload64(const u64* p) {
  return __hip_atomic_load(p, __ATOMIC_RELAXED, __HIP_MEMORY_SCOPE_AGENT);
}

// Validated matvec: load full h-row slice (16 batches x 1024 cols) as atomic u64s,
// run the 32-chunk MFMA chain vs LDS weight row WROW, and validate by NaN-checking
// the accumulator (sentinel qNaN propagates). Retry reloads + recomputes.
#define VALID_MM(P64, WROW, AA, AB)                                           \
  for (;;) {                                                                  \
    u64 hu[64];                                                               \
    _Pragma("unroll")                                                         \
    for (int kk = 0; kk < 32; ++kk) {                                         \
      hu[2 * kk]     = aload64(&(P64)[kk * 8 + fg * 2]);                      \
      hu[2 * kk + 1] = aload64(&(P64)[kk * 8 + fg * 2 + 1]);                  \
    }                                                                         \
    AA = zero; AB = zero;                                                     \
    _Pragma("unroll")                                                         \
    for (int kk = 0; kk < 32; ++kk) {                                         \
      u64x2v tq; tq[0] = hu[2 * kk]; tq[1] = hu[2 * kk + 1];                  \
      bf16x8v hf = __builtin_bit_cast(bf16x8v, tq);                           \
      bf16x8v bw = *(const bf16x8v*)&Ws[(WROW) * LDW + kk * 32 + fg * 8];     \
      if (kk & 1) AB = __builtin_amdgcn_mfma_f32_16x16x32_bf16(hf, bw, AB, 0, 0, 0); \
      else        AA = __builtin_amdgcn_mfma_f32_16x16x32_bf16(hf, bw, AA, 0, 0, 0); \
    }                                                                         \
    int bad = 0;                                                              \
    _Pragma("unroll")                                                         \
    for (int r = 0; r < 4; ++r)                                               \
      bad |= __builtin_isnan(AA[r]) | __builtin_isnan(AB[r]);                 \
    if (!__any(bad)) break;                                                   \
  }

// ---------------- generic fp32 -> bf16 ----------------
__global__ __launch_bounds__(256) void k_f2b(const float* __restrict__ src,
                                             unsigned short* __restrict__ dst, int n) {
  int i = blockIdx.x * 256 + threadIdx.x;
  int stride = gridDim.x * 256;
  for (; i < n; i += stride) dst[i] = f2b(src[i]);
}

// ---------------- sentinel fill (16B granularity) ----------------
__global__ __launch_bounds__(256) void k_sentinel(unsigned int* __restrict__ p, long n4) {
  long i = (long)blockIdx.x * 256 + threadIdx.x;
  long stride = (long)gridDim.x * 256;
  u32x4v s = {SENT, SENT, SENT, SENT};
  for (; i < n4; i += stride) ((u32x4v*)p)[i] = s;
}

// ---------------- biases ----------------
__global__ __launch_bounds__(256) void k_misc(const float* __restrict__ bih0, const float* __restrict__ bhh0,
                                              const float* __restrict__ bih1, const float* __restrict__ bhh1,
                                              float* __restrict__ bias0, float* __restrict__ bias1) {
  int i = blockIdx.x * 256 + threadIdx.x;
  if (i < HID) { bias0[i] = bih0[i] + bhh0[i]; bias1[i] = bih1[i] + bhh1[i]; }
}

// ---------------- hidden = z @ l2h_w + b, torch-reshape to [2][16][1024], bf16 ----------------
__global__ __launch_bounds__(256) void k_latent(const float* __restrict__ z, const float* __restrict__ w,
                                                const float* __restrict__ bvec, unsigned short* __restrict__ h0) {
  int idx = blockIdx.x * 256 + threadIdx.x;          // [0, 2*16*1024)
  int l  = idx >> 14;
  int bb = (idx >> 10) & 15;
  int hh = idx & 1023;
  int b = l * 8 + (bb >> 1);                          // torch flat-reshape mapping
  int j = ((bb & 1) << 10) | hh;
  float s = bvec[j];
  for (int k = 0; k < LAT; ++k) s += z[b * LAT + k] * w[k * (HID * 2) + j];
  h0[idx] = f2b(s);
}

// ---------------- embedding gather -> bf16, [b][t][EMB] ----------------
__global__ __launch_bounds__(256) void k_embed(const float* __restrict__ emb, const int* __restrict__ inp,
                                               unsigned short* __restrict__ x) {
  int row = blockIdx.x;                               // B*S
  int tok = inp[row];
  for (int j = threadIdx.x; j < EMB; j += 256)
    x[(long)row * EMB + j] = f2b(emb[(long)tok * EMB + j]);
}

// ---------------- pred_w [K][N] fp32 -> [N][K] bf16 (tiled transpose) ----------------
__global__ void k_transpose(const float* __restrict__ src, unsigned short* __restrict__ dst) {
  __shared__ float tile[32][33];
  int n0 = blockIdx.x * 32;
  int k0 = blockIdx.y * 32;
  int tx = threadIdx.x, ty = threadIdx.y;
  for (int i = ty; i < 32; i += 8)
    tile[i][tx] = src[(long)(k0 + i) * VOCAB + n0 + tx];
  __syncthreads();
  for (int i = ty; i < 32; i += 8)
    dst[(long)(n0 + i) * HID + k0 + tx] = f2b(tile[tx][i]);
}

// ---------------- C[M][N] = A[M][K] * B[N][K]^T + bias[N]  (bf16 in, OUT out) ----------------
template <typename OUT>
__global__ __launch_bounds__(256) void gemm_bt(const unsigned short* __restrict__ A,
                                               const unsigned short* __restrict__ Bm,
                                               const float* __restrict__ bias,
                                               OUT* __restrict__ C,
                                               int M, int N, int K) {
  const int LDT = 72;                                  // padded LDS K-stride
  extern __shared__ unsigned short smem_g[];
  unsigned short* As = smem_g;
  unsigned short* Bs = smem_g + 128 * LDT;

  int nTn = N >> 7;
  int tm = blockIdx.x / nTn, tn = blockIdx.x % nTn;
  long m0 = (long)tm << 7, n0 = (long)tn << 7;
  int t = threadIdx.x;
  int lane = t & 63, w = t >> 6;
  int wr = (w >> 1) * 64, wc = (w & 1) * 64;
  int fr = lane & 15, fg = lane >> 4;

  f32x4v acc[4][4];
  f32x4v zero = {0.f, 0.f, 0.f, 0.f};
#pragma unroll
  for (int i = 0; i < 4; ++i)
#pragma unroll
    for (int j = 0; j < 4; ++j) acc[i][j] = zero;

  int srow = t >> 3;
  int scol = (t & 7) << 3;

  for (int kt = 0; kt < K; kt += 64) {
#pragma unroll
    for (int it = 0; it < 4; ++it) {
      int row = srow + it * 32;
      bf16x8v va = *(const bf16x8v*)&A[(m0 + row) * K + kt + scol];
      bf16x8v vb = *(const bf16x8v*)&Bm[(n0 + row) * K + kt + scol];
      *(bf16x8v*)&As[row * LDT + scol] = va;
      *(bf16x8v*)&Bs[row * LDT + scol] = vb;
    }
    __syncthreads();
#pragma unroll
    for (int kk = 0; kk < 2; ++kk) {
      int ko = kk * 32 + fg * 8;
      bf16x8v af[4], bfv[4];
#pragma unroll
      for (int i = 0; i < 4; ++i) af[i] = *(const bf16x8v*)&As[(wr + i * 16 + fr) * LDT + ko];
#pragma unroll
      for (int j = 0; j < 4; ++j) bfv[j] = *(const bf16x8v*)&Bs[(wc + j * 16 + fr) * LDT + ko];
#pragma unroll
      for (int i = 0; i < 4; ++i)
#pragma unroll
        for (int j = 0; j < 4; ++j)
          acc[i][j] = __builtin_amdgcn_mfma_f32_16x16x32_bf16(af[i], bfv[j], acc[i][j], 0, 0, 0);
    }
    __syncthreads();
  }

#pragma unroll
  for (int j = 0; j < 4; ++j) {
    long n = n0 + wc + j * 16 + fr;
    float bv = bias[n];
#pragma unroll
    for (int i = 0; i < 4; ++i) {
      long mrow = m0 + wr + i * 16 + fg * 4;
#pragma unroll
      for (int r = 0; r < 4; ++r) {
        float v = acc[i][j][r] + bv;
        if constexpr (__hip_internal::is_same<OUT, float>::value) {
          C[(mrow + r) * (long)N + n] = v;
        } else {
          C[(mrow + r) * (long)N + n] = f2b(v);
        }
      }
    }
  }
}

// ---------------- fused 2-layer pipelined RNN scan, sentinel-synchronized v2 ----------------
// 96 WGs x 128 threads (2 waves), persistent, scan-only dispatch.
//   WG 0..31  (L0): h1[t] = tanh(xw0[t] + h1[t-1] @ Whh0^T); wave w owns 16 cols.
//   WG 32..95 (L1): h2[t] = tanh(h1[t] @ Wih1^T + h2[t-1] @ Whh1^T + bias1), 16 cols;
//                   wave0 = h1-part (+ epilogue), wave1 = h2-part (partial via LDS).
// Sync: NO flags, NO acks. ys0/ys1 pre-filled with qNaN sentinel; producers write
// packed 4B pairs write-through (relaxed agent atomics); consumers load via relaxed
// agent atomic u64s (compiler-managed), run the MFMA chain, and NaN-check the
// accumulator — sentinel propagates to NaN, so a clean acc proves the row was valid.
__global__ __launch_bounds__(128, 1) void k_scan2(const unsigned short* __restrict__ whh0,
                                                  const unsigned short* __restrict__ wih1,
                                                  const unsigned short* __restrict__ whh1,
                                                  const unsigned short* __restrict__ xw0,   // [B][S][H] bf16 (bias0 folded)
                                                  const float* __restrict__ bias1,
                                                  const unsigned short* __restrict__ h0all, // [2][B][H] bf16
                                                  unsigned short* __restrict__ ys0,         // [B][S][H] bf16 (sentinel-filled)
                                                  unsigned short* __restrict__ ys1) {       // [B][S][H] bf16 (sentinel-filled)
  const int LDW = 1032;                                // pad 8: 2-way bank alias only
  extern __shared__ unsigned short Ws[];
  float* Part = (float*)(Ws + 32 * LDW);               // 64 lanes x f32x4 partial
  const int tid = threadIdx.x;
  const int lane = tid & 63;
  const int wv = tid >> 6;
  const int fr = lane & 15, fg = lane >> 4;
  const int wg = blockIdx.x;
  const f32x4v zero = {0.f, 0.f, 0.f, 0.f};

  if (wg < 32) {
    // ================= Layer 0 =================
    const int nbase = wg * 32;
    for (int c = tid; c < 32 * 128; c += 128) {
      int row = c >> 7, col = (c & 127) << 3;
      *(bf16x8v*)&Ws[row * LDW + col] = *(const bf16x8v*)&whh0[(long)(nbase + row) * HID + col];
    }
    __syncthreads();

    const int wrow = wv * 16 + fr;                     // LDS weight row
    const int mycol = nbase + wrow;                    // output column
    const int odd = fr & 1;

    for (int t = 0; t < SS; ++t) {
      // xw prefetch (independent of h) — overlaps the poll latency
      unsigned short xv[4];
#pragma unroll
      for (int r = 0; r < 4; ++r)
        xv[r] = xw0[((long)(fg * 4 + r) * SS + t) * HID + mycol];

      const u64* p64 = (const u64*)((t == 0) ? (h0all + (long)fr * HID)
                                             : (ys0 + ((long)fr * SS + (t - 1)) * HID));
      f32x4v aA, aB;
      VALID_MM(p64, wrow, aA, aB);
      f32x4v acc = aA + aB;

      unsigned av[4], pv[4];
#pragma unroll
      for (int r = 0; r < 4; ++r) {
        av[r] = (unsigned)f2b(fast_tanh(acc[r] + b2f(xv[r])));
        pv[r] = __shfl_xor(av[r], 1);
      }
      if (!odd) {
#pragma unroll
        for (int r = 0; r < 4; ++r)
          __hip_atomic_store((unsigned int*)&ys0[((long)(fg * 4 + r) * SS + t) * HID + mycol],
                             av[r] | (pv[r] << 16), __ATOMIC_RELAXED, __HIP_MEMORY_SCOPE_AGENT);
      }
      // no ack, no flag, no barrier: consumers validate the data itself.
    }
  } else {
    // ================= Layer 1 =================
    const int j = wg - 32;
    const int nbase = j * 16;
    for (int c = tid; c < 32 * 128; c += 128) {
      int row = c >> 7, col = (c & 127) << 3;
      const unsigned short* src = (row < 16) ? &wih1[(long)(nbase + row) * HID + col]
                                             : &whh1[(long)(nbase + row - 16) * HID + col];
      *(bf16x8v*)&Ws[row * LDW + col] = *(const bf16x8v*)src;
    }
    __syncthreads();
    const int odd = fr & 1;

    if (wv == 0) {
      // ---- wave0: h1[t] @ Wih1^T + epilogue ----
      const float bv = bias1[nbase + fr];
      for (int t = 0; t < SS; ++t) {
        const u64* p64 = (const u64*)(ys0 + ((long)fr * SS + t) * HID);
        f32x4v aA, aB;
        VALID_MM(p64, fr, aA, aB);

        __syncthreads();                               // wave1's partial is in LDS
        f32x4v part = *(const f32x4v*)&Part[lane << 2];
        f32x4v sum = (aA + aB) + part;

        unsigned av[4], pv[4];
#pragma unroll
        for (int r = 0; r < 4; ++r) {
          av[r] = (unsigned)f2b(fast_tanh(sum[r] + bv));
          pv[r] = __shfl_xor(av[r], 1);
        }
        if (!odd) {
#pragma unroll
          for (int r = 0; r < 4; ++r)
            __hip_atomic_store((unsigned int*)&ys1[((long)(fg * 4 + r) * SS + t) * HID + nbase + fr],
                               av[r] | (pv[r] << 16), __ATOMIC_RELAXED, __HIP_MEMORY_SCOPE_AGENT);
        }
      }
    } else {
      // ---- wave1: h2[t-1] @ Whh1^T -> LDS partial ----
      for (int t = 0; t < SS; ++t) {
        const u64* p64 = (const u64*)((t == 0) ? (h0all + (long)(BB + fr) * HID)
                                               : (ys1 + ((long)fr * SS + (t - 1)) * HID));
        f32x4v aA, aB;
        VALID_MM(p64, 16 + fr, aA, aB);                // also throttles Part overwrite

        *(f32x4v*)&Part[lane << 2] = aA + aB;          // publish partial
        __syncthreads();                               // wave0 consumes after this
      }
    }
  }
}

extern "C" void kernel_launch(void* const* d_in, const int* in_sizes, int n_in,
                              void* d_out, int out_size, void* d_ws, size_t ws_size,
                              hipStream_t stream) {
  const float* z     = (const float*)d_in[0];
  const int*   inp   = (const int*)d_in[1];
  const float* emb   = (const float*)d_in[2];
  const float* l2h_w = (const float*)d_in[3];
  const float* l2h_b = (const float*)d_in[4];
  const float* wih0  = (const float*)d_in[5];
  const float* whh0  = (const float*)d_in[6];
  const float* bih0  = (const float*)d_in[7];
  const float* bhh0  = (const float*)d_in[8];
  const float* wih1  = (const float*)d_in[9];
  const float* whh1  = (const float*)d_in[10];
  const float* bih1  = (const float*)d_in[11];
  const float* bhh1  = (const float*)d_in[12];
  const float* predw = (const float*)d_in[13];
  const float* predb = (const float*)d_in[14];
  float* out = (float*)d_out;

  char* ws = (char*)d_ws;
  size_t off = 0;
  auto alloc = [&](size_t bytes) {
    char* p = ws + off;
    off = (off + bytes + 255) & ~(size_t)255;
    return p;
  };
  unsigned short* xb     = (unsigned short*)alloc((size_t)BB * SS * EMB * 2);
  unsigned short* wih0b  = (unsigned short*)alloc((size_t)HID * EMB * 2);
  unsigned short* whh0b  = (unsigned short*)alloc((size_t)HID * HID * 2);
  unsigned short* wih1b  = (unsigned short*)alloc((size_t)HID * HID * 2);
  unsigned short* whh1b  = (unsigned short*)alloc((size_t)HID * HID * 2);
  unsigned short* predTb = (unsigned short*)alloc((size_t)VOCAB * HID * 2);
  unsigned short* xw0    = (unsigned short*)alloc((size_t)BB * SS * HID * 2);
  unsigned short* ys0    = (unsigned short*)alloc((size_t)BB * SS * HID * 2);
  unsigned short* ys1    = (unsigned short*)alloc((size_t)BB * SS * HID * 2);
  unsigned short* h0b    = (unsigned short*)alloc((size_t)2 * BB * HID * 2);
  float*          bias0  = (float*)alloc((size_t)HID * 4);
  float*          bias1  = (float*)alloc((size_t)HID * 4);

  // prep
  k_f2b<<<256, 256, 0, stream>>>(wih0, wih0b, HID * EMB);
  k_f2b<<<256, 256, 0, stream>>>(whh0, whh0b, HID * HID);
  k_f2b<<<256, 256, 0, stream>>>(wih1, wih1b, HID * HID);
  k_f2b<<<256, 256, 0, stream>>>(whh1, whh1b, HID * HID);
  k_misc<<<4, 256, 0, stream>>>(bih0, bhh0, bih1, bhh1, bias0, bias1);
  k_latent<<<(2 * BB * HID) / 256, 256, 0, stream>>>(z, l2h_w, l2h_b, h0b);
  k_embed<<<BB * SS, 256, 0, stream>>>(emb, inp, xb);
  k_transpose<<<dim3(VOCAB / 32, HID / 32), dim3(32, 8), 0, stream>>>(predw, predTb);
  // sentinel-fill both h histories (2 x 16MB)
  k_sentinel<<<2048, 256, 0, stream>>>((unsigned int*)ys0, (long)BB * SS * HID / 8);
  k_sentinel<<<2048, 256, 0, stream>>>((unsigned int*)ys1, (long)BB * SS * HID / 8);

  size_t gemm_lds = (size_t)2 * 128 * 72 * 2;
  size_t scan_lds = (size_t)32 * 1032 * 2 + 64 * 4 * 4;  // weights + partial buffer

  // xw0 = x @ w_ih0^T + (b_ih0 + b_hh0)   -> bf16
  gemm_bt<unsigned short><<<(BB * SS / 128) * (HID / 128), 256, gemm_lds, stream>>>(
      xb, wih0b, bias0, xw0, BB * SS, HID, EMB);
  // fused pipelined 2-layer scan (sentinel-synchronized, compiler-visible loads)
  k_scan2<<<96, 128, scan_lds, stream>>>(whh0b, wih1b, whh1b, xw0, bias1, h0b, ys0, ys1);
  // logits = h2 @ pred_w + pred_b  -> fp32 (d_out)
  gemm_bt<float><<<(BB * SS / 128) * (VOCAB / 128), 256, gemm_lds, stream>>>(
      ys1, predTb, predb, out, BB * SS, VOCAB, HID);
}

// Round 10
// 2997.523 us; speedup vs baseline: 1.6680x; 1.6680x over previous
//
#include <hip/hip_runtime.h>
#include <hip/hip_bf16.h>

#define BB 16
#define SS 512
#define VOCAB 32000
#define EMB 512
#define HID 1024
#define LAT 256

typedef __attribute__((ext_vector_type(8))) short bf16x8v;
typedef __attribute__((ext_vector_type(4))) float f32x4v;

__device__ __forceinline__ unsigned short f2b(float f) {
  unsigned int u = __float_as_uint(f);
  unsigned int r = (u + 0x7fffu + ((u >> 16) & 1u)) >> 16;
  return (unsigned short)r;
}

__device__ __forceinline__ float b2f(unsigned short s) {
  return __uint_as_float(((unsigned int)s) << 16);
}

__device__ __forceinline__ float fast_tanh(float x) {
  float t = fminf(fmaxf(x * 2.8853900817779268f, -60.f), 60.f);
  float e = __builtin_amdgcn_exp2f(t);
  return (e - 1.f) * __builtin_amdgcn_rcpf(e + 1.f);
}

// coherent-point 16B load: bypass (possibly stale) L1/L2, read LLC directly.
__device__ __forceinline__ bf16x8v load16_coherent(const unsigned short* p) {
  bf16x8v r;
  asm volatile("global_load_dwordx4 %0, %1, off sc0 sc1"
               : "=v"(r) : "v"(p) : "memory");
  return r;
}

// async global->LDS 16B per lane (lds dest = wave-uniform base + lane*16)
__device__ __forceinline__ void gload_lds16(const unsigned short* g, unsigned short* l) {
  typedef __attribute__((address_space(1))) const unsigned int gu32;
  typedef __attribute__((address_space(3))) unsigned int su32;
  __builtin_amdgcn_global_load_lds((gu32*)g, (su32*)l, 16, 0, 0);
}

// granular vmem wait + scheduling fence (rule #18)
#define WAITV(n)                                                   \
  do {                                                             \
    asm volatile("s_waitcnt vmcnt(" #n ")" ::: "memory");          \
    __builtin_amdgcn_sched_barrier(0);                             \
  } while (0)

// 8-step MFMA chunk: consume HF[K0..K0+8) against LDS weight row WROW into A
#define MCHUNK(HF, WROW, K0, A)                                              \
  _Pragma("unroll")                                                          \
  for (int kk = K0; kk < K0 + 8; ++kk) {                                     \
    bf16x8v bw = *(const bf16x8v*)&Ws[(WROW) * LDW + kk * 32 + fg * 8];      \
    A = __builtin_amdgcn_mfma_f32_16x16x32_bf16(HF[kk], bw, A, 0, 0, 0);     \
  }

// ---------------- generic fp32 -> bf16 ----------------
__global__ __launch_bounds__(256) void k_f2b(const float* __restrict__ src,
                                             unsigned short* __restrict__ dst, int n) {
  int i = blockIdx.x * 256 + threadIdx.x;
  int stride = gridDim.x * 256;
  for (; i < n; i += stride) dst[i] = f2b(src[i]);
}

// ---------------- biases + flag zeroing ----------------
__global__ __launch_bounds__(256) void k_misc(const float* __restrict__ bih0, const float* __restrict__ bhh0,
                                              const float* __restrict__ bih1, const float* __restrict__ bhh1,
                                              float* __restrict__ bias0, float* __restrict__ bias1,
                                              unsigned int* __restrict__ flags, int nflags) {
  int i = blockIdx.x * 256 + threadIdx.x;
  if (i < HID) { bias0[i] = bih0[i] + bhh0[i]; bias1[i] = bih1[i] + bhh1[i]; }
  if (i < nflags) flags[i] = 0u;
}

// ---------------- hidden = z @ l2h_w + b, torch-reshape to [2][16][1024], bf16 ----------------
__global__ __launch_bounds__(256) void k_latent(const float* __restrict__ z, const float* __restrict__ w,
                                                const float* __restrict__ bvec, unsigned short* __restrict__ h0) {
  int idx = blockIdx.x * 256 + threadIdx.x;          // [0, 2*16*1024)
  int l  = idx >> 14;
  int bb = (idx >> 10) & 15;
  int hh = idx & 1023;
  int b = l * 8 + (bb >> 1);                          // torch flat-reshape mapping
  int j = ((bb & 1) << 10) | hh;
  float s = bvec[j];
  for (int k = 0; k < LAT; ++k) s += z[b * LAT + k] * w[k * (HID * 2) + j];
  h0[idx] = f2b(s);
}

// ---------------- embedding gather -> bf16, [b][t][EMB] ----------------
__global__ __launch_bounds__(256) void k_embed(const float* __restrict__ emb, const int* __restrict__ inp,
                                               unsigned short* __restrict__ x) {
  int row = blockIdx.x;                               // B*S
  int tok = inp[row];
  for (int j = threadIdx.x; j < EMB; j += 256)
    x[(long)row * EMB + j] = f2b(emb[(long)tok * EMB + j]);
}

// ---------------- pred_w [K][N] fp32 -> [N][K] bf16 (tiled transpose) ----------------
__global__ void k_transpose(const float* __restrict__ src, unsigned short* __restrict__ dst) {
  __shared__ float tile[32][33];
  int n0 = blockIdx.x * 32;
  int k0 = blockIdx.y * 32;
  int tx = threadIdx.x, ty = threadIdx.y;
  for (int i = ty; i < 32; i += 8)
    tile[i][tx] = src[(long)(k0 + i) * VOCAB + n0 + tx];
  __syncthreads();
  for (int i = ty; i < 32; i += 8)
    dst[(long)(n0 + i) * HID + k0 + tx] = f2b(tile[tx][i]);
}

// ---------------- C[M][N] = A[M][K] * B[N][K]^T + bias[N]  (bf16 in, OUT out) ----------------
// m97-style: 128x128 tile, BK=64, linear LDS [128][64], 16B global_load_lds staging.
template <typename OUT>
__global__ __launch_bounds__(256) void gemm_bt(const unsigned short* __restrict__ A,
                                               const unsigned short* __restrict__ Bm,
                                               const float* __restrict__ bias,
                                               OUT* __restrict__ C,
                                               int M, int N, int K) {
  extern __shared__ unsigned short smem_g[];
  unsigned short* As = smem_g;                         // [128][64] linear
  unsigned short* Bs = smem_g + 128 * 64;              // [128][64] linear

  int nTn = N >> 7;
  int tm = blockIdx.x / nTn, tn = blockIdx.x % nTn;
  long m0 = (long)tm << 7, n0 = (long)tn << 7;
  int t = threadIdx.x;
  int lane = t & 63, w = t >> 6;
  int wr = (w >> 1) * 64, wc = (w & 1) * 64;
  int fr = lane & 15, fg = lane >> 4;

  f32x4v acc[4][4];
  f32x4v zero = {0.f, 0.f, 0.f, 0.f};
#pragma unroll
  for (int i = 0; i < 4; ++i)
#pragma unroll
    for (int j = 0; j < 4; ++j) acc[i][j] = zero;

  const int lrow = lane >> 3;                          // 0..7 within 8-row block
  const int lcol = (lane & 7) * 8;                     // bf16 col within BK=64

  for (int kt = 0; kt < K; kt += 64) {
    // stage A/B tiles: each wave stages rows [w*32, w*32+32) in 4 blocks of 8 rows
#pragma unroll
    for (int c = 0; c < 4; ++c) {
      int rbase = w * 32 + c * 8;
      gload_lds16(&A[(m0 + rbase + lrow) * (long)K + kt + lcol], &As[rbase * 64]);
      gload_lds16(&Bm[(n0 + rbase + lrow) * (long)K + kt + lcol], &Bs[rbase * 64]);
    }
    __syncthreads();
#pragma unroll
    for (int kk = 0; kk < 2; ++kk) {
      int ko = kk * 32 + fg * 8;
      bf16x8v af[4], bfv[4];
#pragma unroll
      for (int i = 0; i < 4; ++i) af[i] = *(const bf16x8v*)&As[(wr + i * 16 + fr) * 64 + ko];
#pragma unroll
      for (int j = 0; j < 4; ++j) bfv[j] = *(const bf16x8v*)&Bs[(wc + j * 16 + fr) * 64 + ko];
#pragma unroll
      for (int i = 0; i < 4; ++i)
#pragma unroll
        for (int j = 0; j < 4; ++j)
          acc[i][j] = __builtin_amdgcn_mfma_f32_16x16x32_bf16(af[i], bfv[j], acc[i][j], 0, 0, 0);
    }
    __syncthreads();
  }

#pragma unroll
  for (int j = 0; j < 4; ++j) {
    long n = n0 + wc + j * 16 + fr;
    float bv = bias[n];
#pragma unroll
    for (int i = 0; i < 4; ++i) {
      long mrow = m0 + wr + i * 16 + fg * 4;
#pragma unroll
      for (int r = 0; r < 4; ++r) {
        float v = acc[i][j][r] + bv;
        if constexpr (__hip_internal::is_same<OUT, float>::value) {
          C[(mrow + r) * (long)N + n] = v;
        } else {
          C[(mrow + r) * (long)N + n] = f2b(v);
        }
      }
    }
  }
}

// ---------------- fused 2-layer pipelined RNN scan (round-5 proven image) ----------------
// 96 WGs x 128 threads (2 waves), persistent. Max 32 in-flight asm loads per wave.
//   WG 0..31  (L0): h1[t] = tanh(xw0[t] + h1[t-1] @ Whh0^T); wave w owns 16 cols.
//   WG 32..95 (L1): h2[t] = tanh(h1[t] @ Wih1^T + h2[t-1] @ Whh1^T + bias1), 16 cols;
//                   wave0 = h1-part (+ epilogue), wave1 = h2-part (partial via LDS).
// Broadcast: relaxed agent-atomic write-through stores; sc0/sc1 bypass loads;
// per-WG flag lines; producer does vmcnt(0) ack before flag store.
__global__ __launch_bounds__(128, 1) void k_scan2(const unsigned short* __restrict__ whh0,
                                                  const unsigned short* __restrict__ wih1,
                                                  const unsigned short* __restrict__ whh1,
                                                  const unsigned short* __restrict__ xw0,   // [B][S][H] bf16 (bias0 folded)
                                                  const float* __restrict__ bias1,
                                                  const unsigned short* __restrict__ h0all, // [2][B][H] bf16
                                                  unsigned short* __restrict__ ys0,         // [B][S][H] bf16
                                                  unsigned short* __restrict__ ys1,         // [B][S][H] bf16
                                                  unsigned int* __restrict__ flags) {       // flag0: [i*16]; flag1: [1024+j*16]
  const int LDW = 1032;                                // pad 8: 2-way bank alias only
  extern __shared__ unsigned short Ws[];
  float* Part = (float*)(Ws + 32 * LDW);               // 64 lanes x f32x4 partial
  const int tid = threadIdx.x;
  const int lane = tid & 63;
  const int wv = tid >> 6;
  const int fr = lane & 15, fg = lane >> 4;
  const int wg = blockIdx.x;
  const f32x4v zero = {0.f, 0.f, 0.f, 0.f};

  if (wg < 32) {
    // ================= Layer 0 =================
    const int nbase = wg * 32;
    for (int c = tid; c < 32 * 128; c += 128) {
      int row = c >> 7, col = (c & 127) << 3;
      *(bf16x8v*)&Ws[row * LDW + col] = *(const bf16x8v*)&whh0[(long)(nbase + row) * HID + col];
    }
    __syncthreads();

    const int wrow = wv * 16 + fr;                     // LDS weight row
    const int mycol = nbase + wrow;                    // output column
    const int odd = fr & 1;

    for (int t = 0; t < SS; ++t) {
      // xw prefetch (independent of h) — overlaps the poll
      unsigned short xv[4];
#pragma unroll
      for (int r = 0; r < 4; ++r)
        xv[r] = xw0[((long)(fg * 4 + r) * SS + t) * HID + mycol];

      if (t > 0) {
        unsigned tgt = (unsigned)t;
        for (;;) {
          unsigned v = 0xffffffffu;
          if (lane < 32)
            v = __hip_atomic_load(&flags[lane << 4], __ATOMIC_RELAXED, __HIP_MEMORY_SCOPE_AGENT);
          if (__all(v >= tgt)) break;
        }
      }
      const unsigned short* hp = (t == 0) ? (h0all + (long)fr * HID)
                                          : (ys0 + ((long)fr * SS + (t - 1)) * HID);
      bf16x8v hf[32];
#pragma unroll
      for (int kk = 0; kk < 32; ++kk) hf[kk] = load16_coherent(&hp[kk * 32 + fg * 8]);
      __builtin_amdgcn_sched_barrier(0);

      f32x4v aA = zero, aB = zero;
      WAITV(24); MCHUNK(hf, wrow, 0,  aA);
      WAITV(16); MCHUNK(hf, wrow, 8,  aB);
      WAITV(8);  MCHUNK(hf, wrow, 16, aA);
      WAITV(0);  MCHUNK(hf, wrow, 24, aB);
      f32x4v acc = aA + aB;

      unsigned av[4], pv[4];
#pragma unroll
      for (int r = 0; r < 4; ++r) {
        av[r] = (unsigned)f2b(fast_tanh(acc[r] + b2f(xv[r])));
        pv[r] = __shfl_xor(av[r], 1);
      }
      if (!odd) {
#pragma unroll
        for (int r = 0; r < 4; ++r)
          __hip_atomic_store((unsigned int*)&ys0[((long)(fg * 4 + r) * SS + t) * HID + mycol],
                             av[r] | (pv[r] << 16), __ATOMIC_RELAXED, __HIP_MEMORY_SCOPE_AGENT);
      }
      WAITV(0);                                        // stores ack'd at coherence point
      __syncthreads();                                 // both waves done
      if (tid == 0)
        __hip_atomic_store(&flags[wg << 4], (unsigned)(t + 1),
                           __ATOMIC_RELAXED, __HIP_MEMORY_SCOPE_AGENT);
    }
  } else {
    // ================= Layer 1 =================
    const int j = wg - 32;
    const int nbase = j * 16;
    for (int c = tid; c < 32 * 128; c += 128) {
      int row = c >> 7, col = (c & 127) << 3;
      const unsigned short* src = (row < 16) ? &wih1[(long)(nbase + row) * HID + col]
                                             : &whh1[(long)(nbase + row - 16) * HID + col];
      *(bf16x8v*)&Ws[row * LDW + col] = *(const bf16x8v*)src;
    }
    __syncthreads();
    const int odd = fr & 1;

    if (wv == 0) {
      // ---- wave0: h1[t] @ Wih1^T + epilogue ----
      const float bv = bias1[nbase + fr];
      for (int t = 0; t < SS; ++t) {
        {
          unsigned tgt = (unsigned)(t + 1);            // L0 finished step t
          for (;;) {
            unsigned v = 0xffffffffu;
            if (lane < 32)
              v = __hip_atomic_load(&flags[lane << 4], __ATOMIC_RELAXED, __HIP_MEMORY_SCOPE_AGENT);
            if (__all(v >= tgt)) break;
          }
        }
        const unsigned short* hp1 = ys0 + ((long)fr * SS + t) * HID;
        bf16x8v hf[32];
#pragma unroll
        for (int kk = 0; kk < 32; ++kk) hf[kk] = load16_coherent(&hp1[kk * 32 + fg * 8]);
        __builtin_amdgcn_sched_barrier(0);

        f32x4v aA = zero, aB = zero;
        WAITV(24); MCHUNK(hf, fr, 0,  aA);
        WAITV(16); MCHUNK(hf, fr, 8,  aB);
        WAITV(8);  MCHUNK(hf, fr, 16, aA);
        WAITV(0);  MCHUNK(hf, fr, 24, aB);

        __syncthreads();                               // wave1's partial is in LDS
        f32x4v part = *(const f32x4v*)&Part[lane << 2];
        f32x4v sum = (aA + aB) + part;

        unsigned av[4], pv[4];
#pragma unroll
        for (int r = 0; r < 4; ++r) {
          av[r] = (unsigned)f2b(fast_tanh(sum[r] + bv));
          pv[r] = __shfl_xor(av[r], 1);
        }
        if (!odd) {
#pragma unroll
          for (int r = 0; r < 4; ++r)
            __hip_atomic_store((unsigned int*)&ys1[((long)(fg * 4 + r) * SS + t) * HID + nbase + fr],
                               av[r] | (pv[r] << 16), __ATOMIC_RELAXED, __HIP_MEMORY_SCOPE_AGENT);
        }
        WAITV(0);                                      // h2 stores ack'd
        if (lane == 0)
          __hip_atomic_store(&flags[1024 + (j << 4)], (unsigned)(t + 1),
                             __ATOMIC_RELAXED, __HIP_MEMORY_SCOPE_AGENT);
      }
    } else {
      // ---- wave1: h2[t-1] @ Whh1^T -> LDS partial ----
      for (int t = 0; t < SS; ++t) {
        if (t > 0) {
          unsigned tgt = (unsigned)t;                  // all L1 WGs finished step t-1
          for (;;) {
            unsigned v = __hip_atomic_load(&flags[1024 + (lane << 4)],
                                           __ATOMIC_RELAXED, __HIP_MEMORY_SCOPE_AGENT);
            if (__all(v >= tgt)) break;
          }
        }
        const unsigned short* hp2 = (t == 0) ? (h0all + (long)(BB + fr) * HID)
                                             : (ys1 + ((long)fr * SS + (t - 1)) * HID);
        bf16x8v hf[32];
#pragma unroll
        for (int kk = 0; kk < 32; ++kk) hf[kk] = load16_coherent(&hp2[kk * 32 + fg * 8]);
        __builtin_amdgcn_sched_barrier(0);

        f32x4v aA = zero, aB = zero;
        WAITV(24); MCHUNK(hf, 16 + fr, 0,  aA);
        WAITV(16); MCHUNK(hf, 16 + fr, 8,  aB);
        WAITV(8);  MCHUNK(hf, 16 + fr, 16, aA);
        WAITV(0);  MCHUNK(hf, 16 + fr, 24, aB);

        *(f32x4v*)&Part[lane << 2] = aA + aB;          // publish partial
        __syncthreads();                               // wave0 consumes after this
      }
    }
  }
}

extern "C" void kernel_launch(void* const* d_in, const int* in_sizes, int n_in,
                              void* d_out, int out_size, void* d_ws, size_t ws_size,
                              hipStream_t stream) {
  const float* z     = (const float*)d_in[0];
  const int*   inp   = (const int*)d_in[1];
  const float* emb   = (const float*)d_in[2];
  const float* l2h_w = (const float*)d_in[3];
  const float* l2h_b = (const float*)d_in[4];
  const float* wih0  = (const float*)d_in[5];
  const float* whh0  = (const float*)d_in[6];
  const float* bih0  = (const float*)d_in[7];
  const float* bhh0  = (const float*)d_in[8];
  const float* wih1  = (const float*)d_in[9];
  const float* whh1  = (const float*)d_in[10];
  const float* bih1  = (const float*)d_in[11];
  const float* bhh1  = (const float*)d_in[12];
  const float* predw = (const float*)d_in[13];
  const float* predb = (const float*)d_in[14];
  float* out = (float*)d_out;

  char* ws = (char*)d_ws;
  size_t off = 0;
  auto alloc = [&](size_t bytes) {
    char* p = ws + off;
    off = (off + bytes + 255) & ~(size_t)255;
    return p;
  };
  unsigned short* xb     = (unsigned short*)alloc((size_t)BB * SS * EMB * 2);
  unsigned short* wih0b  = (unsigned short*)alloc((size_t)HID * EMB * 2);
  unsigned short* whh0b  = (unsigned short*)alloc((size_t)HID * HID * 2);
  unsigned short* wih1b  = (unsigned short*)alloc((size_t)HID * HID * 2);
  unsigned short* whh1b  = (unsigned short*)alloc((size_t)HID * HID * 2);
  unsigned short* predTb = (unsigned short*)alloc((size_t)VOCAB * HID * 2);
  unsigned short* xw0    = (unsigned short*)alloc((size_t)BB * SS * HID * 2);
  unsigned short* ys0    = (unsigned short*)alloc((size_t)BB * SS * HID * 2);
  unsigned short* ys1    = (unsigned short*)alloc((size_t)BB * SS * HID * 2);
  unsigned short* h0b    = (unsigned short*)alloc((size_t)2 * BB * HID * 2);
  float*          bias0  = (float*)alloc((size_t)HID * 4);
  float*          bias1  = (float*)alloc((size_t)HID * 4);
  unsigned int*   flags  = (unsigned int*)alloc((size_t)2048 * 4);  // flag0[32*16] + flag1[64*16]

  // prep
  k_f2b<<<256, 256, 0, stream>>>(wih0, wih0b, HID * EMB);
  k_f2b<<<256, 256, 0, stream>>>(whh0, whh0b, HID * HID);
  k_f2b<<<256, 256, 0, stream>>>(wih1, wih1b, HID * HID);
  k_f2b<<<256, 256, 0, stream>>>(whh1, whh1b, HID * HID);
  k_misc<<<8, 256, 0, stream>>>(bih0, bhh0, bih1, bhh1, bias0, bias1, flags, 2048);
  k_latent<<<(2 * BB * HID) / 256, 256, 0, stream>>>(z, l2h_w, l2h_b, h0b);
  k_embed<<<BB * SS, 256, 0, stream>>>(emb, inp, xb);
  k_transpose<<<dim3(VOCAB / 32, HID / 32), dim3(32, 8), 0, stream>>>(predw, predTb);

  size_t gemm_lds = (size_t)2 * 128 * 64 * 2;            // 32KB linear
  size_t scan_lds = (size_t)32 * 1032 * 2 + 64 * 4 * 4;  // weights + partial buffer

  // xw0 = x @ w_ih0^T + (b_ih0 + b_hh0)   -> bf16
  gemm_bt<unsigned short><<<(BB * SS / 128) * (HID / 128), 256, gemm_lds, stream>>>(
      xb, wih0b, bias0, xw0, BB * SS, HID, EMB);
  // fused pipelined 2-layer scan (round-5 proven)
  k_scan2<<<96, 128, scan_lds, stream>>>(whh0b, wih1b, whh1b, xw0, bias1, h0b, ys0, ys1, flags);
  // logits = h2 @ pred_w + pred_b  -> fp32 (d_out)
  gemm_bt<float><<<(BB * SS / 128) * (VOCAB / 128), 256, gemm_lds, stream>>>(
      ys1, predTb, predb, out, BB * SS, VOCAB, HID);
}

// Round 11
// 2996.850 us; speedup vs baseline: 1.6683x; 1.0002x over previous
//
#include <hip/hip_runtime.h>
#include <hip/hip_bf16.h>

#define BB 16
#define SS 512
#define VOCAB 32000
#define EMB 512
#define HID 1024
#define LAT 256

typedef __attribute__((ext_vector_type(8))) short bf16x8v;
typedef __attribute__((ext_vector_type(4))) float f32x4v;

__device__ __forceinline__ unsigned short f2b(float f) {
  unsigned int u = __float_as_uint(f);
  unsigned int r = (u + 0x7fffu + ((u >> 16) & 1u)) >> 16;
  return (unsigned short)r;
}

__device__ __forceinline__ float b2f(unsigned short s) {
  return __uint_as_float(((unsigned int)s) << 16);
}

__device__ __forceinline__ float fast_tanh(float x) {
  float t = fminf(fmaxf(x * 2.8853900817779268f, -60.f), 60.f);
  float e = __builtin_amdgcn_exp2f(t);
  return (e - 1.f) * __builtin_amdgcn_rcpf(e + 1.f);
}

// coherent-point 16B load: bypass (possibly stale) L1/L2, read LLC directly.
__device__ __forceinline__ bf16x8v load16_coherent(const unsigned short* p) {
  bf16x8v r;
  asm volatile("global_load_dwordx4 %0, %1, off sc0 sc1"
               : "=v"(r) : "v"(p) : "memory");
  return r;
}

// async global->LDS 16B per lane (lds dest = wave-uniform base + lane*16)
__device__ __forceinline__ void gload_lds16(const unsigned short* g, unsigned short* l) {
  typedef __attribute__((address_space(1))) const unsigned int gu32;
  typedef __attribute__((address_space(3))) unsigned int su32;
  __builtin_amdgcn_global_load_lds((gu32*)g, (su32*)l, 16, 0, 0);
}

// granular vmem wait + scheduling fence (rule #18)
#define WAITV(n)                                                   \
  do {                                                             \
    asm volatile("s_waitcnt vmcnt(" #n ")" ::: "memory");          \
    __builtin_amdgcn_sched_barrier(0);                             \
  } while (0)

// 8-step MFMA chunk: consume HF[K0..K0+8) against LDS weight row WROW into A
#define MCHUNK(HF, WROW, K0, A)                                              \
  _Pragma("unroll")                                                          \
  for (int kk = K0; kk < K0 + 8; ++kk) {                                     \
    bf16x8v bw = *(const bf16x8v*)&Ws[(WROW) * LDW + kk * 32 + fg * 8];      \
    A = __builtin_amdgcn_mfma_f32_16x16x32_bf16(HF[kk], bw, A, 0, 0, 0);     \
  }

// ---------------- generic fp32 -> bf16 ----------------
__global__ __launch_bounds__(256) void k_f2b(const float* __restrict__ src,
                                             unsigned short* __restrict__ dst, int n) {
  int i = blockIdx.x * 256 + threadIdx.x;
  int stride = gridDim.x * 256;
  for (; i < n; i += stride) dst[i] = f2b(src[i]);
}

// ---------------- biases + flag zeroing ----------------
__global__ __launch_bounds__(256) void k_misc(const float* __restrict__ bih0, const float* __restrict__ bhh0,
                                              const float* __restrict__ bih1, const float* __restrict__ bhh1,
                                              float* __restrict__ bias0, float* __restrict__ bias1,
                                              unsigned int* __restrict__ flags, int nflags) {
  int i = blockIdx.x * 256 + threadIdx.x;
  if (i < HID) { bias0[i] = bih0[i] + bhh0[i]; bias1[i] = bih1[i] + bhh1[i]; }
  if (i < nflags) flags[i] = 0u;
}

// ---------------- hidden = z @ l2h_w + b, torch-reshape to [2][16][1024], bf16 ----------------
__global__ __launch_bounds__(256) void k_latent(const float* __restrict__ z, const float* __restrict__ w,
                                                const float* __restrict__ bvec, unsigned short* __restrict__ h0) {
  int idx = blockIdx.x * 256 + threadIdx.x;          // [0, 2*16*1024)
  int l  = idx >> 14;
  int bb = (idx >> 10) & 15;
  int hh = idx & 1023;
  int b = l * 8 + (bb >> 1);                          // torch flat-reshape mapping
  int j = ((bb & 1) << 10) | hh;
  float s = bvec[j];
  for (int k = 0; k < LAT; ++k) s += z[b * LAT + k] * w[k * (HID * 2) + j];
  h0[idx] = f2b(s);
}

// ---------------- embedding gather -> bf16, [b][t][EMB] ----------------
__global__ __launch_bounds__(256) void k_embed(const float* __restrict__ emb, const int* __restrict__ inp,
                                               unsigned short* __restrict__ x) {
  int row = blockIdx.x;                               // B*S
  int tok = inp[row];
  for (int j = threadIdx.x; j < EMB; j += 256)
    x[(long)row * EMB + j] = f2b(emb[(long)tok * EMB + j]);
}

// ---------------- pred_w [K][N] fp32 -> [N][K] bf16 (tiled transpose) ----------------
__global__ void k_transpose(const float* __restrict__ src, unsigned short* __restrict__ dst) {
  __shared__ float tile[32][33];
  int n0 = blockIdx.x * 32;
  int k0 = blockIdx.y * 32;
  int tx = threadIdx.x, ty = threadIdx.y;
  for (int i = ty; i < 32; i += 8)
    tile[i][tx] = src[(long)(k0 + i) * VOCAB + n0 + tx];
  __syncthreads();
  for (int i = ty; i < 32; i += 8)
    dst[(long)(n0 + i) * HID + k0 + tx] = f2b(tile[tx][i]);
}

// ---------------- C[M][N] = A[M][K] * B[N][K]^T + bias[N]  (bf16 in, OUT out) ----------------
// m97-style: 128x128 tile, BK=64, linear LDS [128][64], 16B global_load_lds staging.
template <typename OUT>
__global__ __launch_bounds__(256) void gemm_bt(const unsigned short* __restrict__ A,
                                               const unsigned short* __restrict__ Bm,
                                               const float* __restrict__ bias,
                                               OUT* __restrict__ C,
                                               int M, int N, int K) {
  extern __shared__ unsigned short smem_g[];
  unsigned short* As = smem_g;                         // [128][64] linear
  unsigned short* Bs = smem_g + 128 * 64;              // [128][64] linear

  int nTn = N >> 7;
  int tm = blockIdx.x / nTn, tn = blockIdx.x % nTn;
  long m0 = (long)tm << 7, n0 = (long)tn << 7;
  int t = threadIdx.x;
  int lane = t & 63, w = t >> 6;
  int wr = (w >> 1) * 64, wc = (w & 1) * 64;
  int fr = lane & 15, fg = lane >> 4;

  f32x4v acc[4][4];
  f32x4v zero = {0.f, 0.f, 0.f, 0.f};
#pragma unroll
  for (int i = 0; i < 4; ++i)
#pragma unroll
    for (int j = 0; j < 4; ++j) acc[i][j] = zero;

  const int lrow = lane >> 3;                          // 0..7 within 8-row block
  const int lcol = (lane & 7) * 8;                     // bf16 col within BK=64

  for (int kt = 0; kt < K; kt += 64) {
    // stage A/B tiles: each wave stages rows [w*32, w*32+32) in 4 blocks of 8 rows
#pragma unroll
    for (int c = 0; c < 4; ++c) {
      int rbase = w * 32 + c * 8;
      gload_lds16(&A[(m0 + rbase + lrow) * (long)K + kt + lcol], &As[rbase * 64]);
      gload_lds16(&Bm[(n0 + rbase + lrow) * (long)K + kt + lcol], &Bs[rbase * 64]);
    }
    __syncthreads();
#pragma unroll
    for (int kk = 0; kk < 2; ++kk) {
      int ko = kk * 32 + fg * 8;
      bf16x8v af[4], bfv[4];
#pragma unroll
      for (int i = 0; i < 4; ++i) af[i] = *(const bf16x8v*)&As[(wr + i * 16 + fr) * 64 + ko];
#pragma unroll
      for (int j = 0; j < 4; ++j) bfv[j] = *(const bf16x8v*)&Bs[(wc + j * 16 + fr) * 64 + ko];
#pragma unroll
      for (int i = 0; i < 4; ++i)
#pragma unroll
        for (int j = 0; j < 4; ++j)
          acc[i][j] = __builtin_amdgcn_mfma_f32_16x16x32_bf16(af[i], bfv[j], acc[i][j], 0, 0, 0);
    }
    __syncthreads();
  }

#pragma unroll
  for (int j = 0; j < 4; ++j) {
    long n = n0 + wc + j * 16 + fr;
    float bv = bias[n];
#pragma unroll
    for (int i = 0; i < 4; ++i) {
      long mrow = m0 + wr + i * 16 + fg * 4;
#pragma unroll
      for (int r = 0; r < 4; ++r) {
        float v = acc[i][j][r] + bv;
        if constexpr (__hip_internal::is_same<OUT, float>::value) {
          C[(mrow + r) * (long)N + n] = v;
        } else {
          C[(mrow + r) * (long)N + n] = f2b(v);
        }
      }
    }
  }
}

// ---------------- fused 2-layer pipelined RNN scan (round-5 proven image) ----------------
// 96 WGs x 128 threads (2 waves), persistent. Max 32 in-flight asm loads per wave.
//   WG 0..31  (L0): h1[t] = tanh(xw0[t] + h1[t-1] @ Whh0^T); wave w owns 16 cols.
//   WG 32..95 (L1): h2[t] = tanh(h1[t] @ Wih1^T + h2[t-1] @ Whh1^T + bias1), 16 cols;
//                   wave0 = h1-part (+ epilogue), wave1 = h2-part (partial via LDS).
// Broadcast: relaxed agent-atomic write-through stores; sc0/sc1 bypass loads;
// per-WG flag lines; producer does vmcnt(0) ack before flag store.
__global__ __launch_bounds__(128, 1) void k_scan2(const unsigned short* __restrict__ whh0,
                                                  const unsigned short* __restrict__ wih1,
                                                  const unsigned short* __restrict__ whh1,
                                                  const unsigned short* __restrict__ xw0,   // [B][S][H] bf16 (bias0 folded)
                                                  const float* __restrict__ bias1,
                                                  const unsigned short* __restrict__ h0all, // [2][B][H] bf16
                                                  unsigned short* __restrict__ ys0,         // [B][S][H] bf16
                                                  unsigned short* __restrict__ ys1,         // [B][S][H] bf16
                                                  unsigned int* __restrict__ flags) {       // flag0: [i*16]; flag1: [1024+j*16]
  const int LDW = 1032;                                // pad 8: 2-way bank alias only
  extern __shared__ unsigned short Ws[];
  float* Part = (float*)(Ws + 32 * LDW);               // 64 lanes x f32x4 partial
  const int tid = threadIdx.x;
  const int lane = tid & 63;
  const int wv = tid >> 6;
  const int fr = lane & 15, fg = lane >> 4;
  const int wg = blockIdx.x;
  const f32x4v zero = {0.f, 0.f, 0.f, 0.f};

  if (wg < 32) {
    // ================= Layer 0 =================
    const int nbase = wg * 32;
    for (int c = tid; c < 32 * 128; c += 128) {
      int row = c >> 7, col = (c & 127) << 3;
      *(bf16x8v*)&Ws[row * LDW + col] = *(const bf16x8v*)&whh0[(long)(nbase + row) * HID + col];
    }
    __syncthreads();

    const int wrow = wv * 16 + fr;                     // LDS weight row
    const int mycol = nbase + wrow;                    // output column
    const int odd = fr & 1;

    for (int t = 0; t < SS; ++t) {
      // xw prefetch (independent of h) — overlaps the poll
      unsigned short xv[4];
#pragma unroll
      for (int r = 0; r < 4; ++r)
        xv[r] = xw0[((long)(fg * 4 + r) * SS + t) * HID + mycol];

      if (t > 0) {
        unsigned tgt = (unsigned)t;
        for (;;) {
          unsigned v = 0xffffffffu;
          if (lane < 32)
            v = __hip_atomic_load(&flags[lane << 4], __ATOMIC_RELAXED, __HIP_MEMORY_SCOPE_AGENT);
          if (__all(v >= tgt)) break;
        }
      }
      const unsigned short* hp = (t == 0) ? (h0all + (long)fr * HID)
                                          : (ys0 + ((long)fr * SS + (t - 1)) * HID);
      bf16x8v hf[32];
#pragma unroll
      for (int kk = 0; kk < 32; ++kk) hf[kk] = load16_coherent(&hp[kk * 32 + fg * 8]);
      __builtin_amdgcn_sched_barrier(0);

      f32x4v aA = zero, aB = zero;
      WAITV(24); MCHUNK(hf, wrow, 0,  aA);
      WAITV(16); MCHUNK(hf, wrow, 8,  aB);
      WAITV(8);  MCHUNK(hf, wrow, 16, aA);
      WAITV(0);  MCHUNK(hf, wrow, 24, aB);
      f32x4v acc = aA + aB;

      unsigned av[4], pv[4];
#pragma unroll
      for (int r = 0; r < 4; ++r) {
        av[r] = (unsigned)f2b(fast_tanh(acc[r] + b2f(xv[r])));
        pv[r] = __shfl_xor(av[r], 1);
      }
      if (!odd) {
#pragma unroll
        for (int r = 0; r < 4; ++r)
          __hip_atomic_store((unsigned int*)&ys0[((long)(fg * 4 + r) * SS + t) * HID + mycol],
                             av[r] | (pv[r] << 16), __ATOMIC_RELAXED, __HIP_MEMORY_SCOPE_AGENT);
      }
      WAITV(0);                                        // stores ack'd at coherence point
      __syncthreads();                                 // both waves done
      if (tid == 0)
        __hip_atomic_store(&flags[wg << 4], (unsigned)(t + 1),
                           __ATOMIC_RELAXED, __HIP_MEMORY_SCOPE_AGENT);
    }
  } else {
    // ================= Layer 1 =================
    const int j = wg - 32;
    const int nbase = j * 16;
    for (int c = tid; c < 32 * 128; c += 128) {
      int row = c >> 7, col = (c & 127) << 3;
      const unsigned short* src = (row < 16) ? &wih1[(long)(nbase + row) * HID + col]
                                             : &whh1[(long)(nbase + row - 16) * HID + col];
      *(bf16x8v*)&Ws[row * LDW + col] = *(const bf16x8v*)src;
    }
    __syncthreads();
    const int odd = fr & 1;

    if (wv == 0) {
      // ---- wave0: h1[t] @ Wih1^T + epilogue ----
      const float bv = bias1[nbase + fr];
      for (int t = 0; t < SS; ++t) {
        {
          unsigned tgt = (unsigned)(t + 1);            // L0 finished step t
          for (;;) {
            unsigned v = 0xffffffffu;
            if (lane < 32)
              v = __hip_atomic_load(&flags[lane << 4], __ATOMIC_RELAXED, __HIP_MEMORY_SCOPE_AGENT);
            if (__all(v >= tgt)) break;
          }
        }
        const unsigned short* hp1 = ys0 + ((long)fr * SS + t) * HID;
        bf16x8v hf[32];
#pragma unroll
        for (int kk = 0; kk < 32; ++kk) hf[kk] = load16_coherent(&hp1[kk * 32 + fg * 8]);
        __builtin_amdgcn_sched_barrier(0);

        f32x4v aA = zero, aB = zero;
        WAITV(24); MCHUNK(hf, fr, 0,  aA);
        WAITV(16); MCHUNK(hf, fr, 8,  aB);
        WAITV(8);  MCHUNK(hf, fr, 16, aA);
        WAITV(0);  MCHUNK(hf, fr, 24, aB);

        __syncthreads();                               // wave1's partial is in LDS
        f32x4v part = *(const f32x4v*)&Part[lane << 2];
        f32x4v sum = (aA + aB) + part;

        unsigned av[4], pv[4];
#pragma unroll
        for (int r = 0; r < 4; ++r) {
          av[r] = (unsigned)f2b(fast_tanh(sum[r] + bv));
          pv[r] = __shfl_xor(av[r], 1);
        }
        if (!odd) {
#pragma unroll
          for (int r = 0; r < 4; ++r)
            __hip_atomic_store((unsigned int*)&ys1[((long)(fg * 4 + r) * SS + t) * HID + nbase + fr],
                               av[r] | (pv[r] << 16), __ATOMIC_RELAXED, __HIP_MEMORY_SCOPE_AGENT);
        }
        WAITV(0);                                      // h2 stores ack'd
        if (lane == 0)
          __hip_atomic_store(&flags[1024 + (j << 4)], (unsigned)(t + 1),
                             __ATOMIC_RELAXED, __HIP_MEMORY_SCOPE_AGENT);
      }
    } else {
      // ---- wave1: h2[t-1] @ Whh1^T -> LDS partial ----
      for (int t = 0; t < SS; ++t) {
        if (t > 0) {
          unsigned tgt = (unsigned)t;                  // all L1 WGs finished step t-1
          for (;;) {
            unsigned v = __hip_atomic_load(&flags[1024 + (lane << 4)],
                                           __ATOMIC_RELAXED, __HIP_MEMORY_SCOPE_AGENT);
            if (__all(v >= tgt)) break;
          }
        }
        const unsigned short* hp2 = (t == 0) ? (h0all + (long)(BB + fr) * HID)
                                             : (ys1 + ((long)fr * SS + (t - 1)) * HID);
        bf16x8v hf[32];
#pragma unroll
        for (int kk = 0; kk < 32; ++kk) hf[kk] = load16_coherent(&hp2[kk * 32 + fg * 8]);
        __builtin_amdgcn_sched_barrier(0);

        f32x4v aA = zero, aB = zero;
        WAITV(24); MCHUNK(hf, 16 + fr, 0,  aA);
        WAITV(16); MCHUNK(hf, 16 + fr, 8,  aB);
        WAITV(8);  MCHUNK(hf, 16 + fr, 16, aA);
        WAITV(0);  MCHUNK(hf, 16 + fr, 24, aB);

        *(f32x4v*)&Part[lane << 2] = aA + aB;          // publish partial
        __syncthreads();                               // wave0 consumes after this
      }
    }
  }
}

extern "C" void kernel_launch(void* const* d_in, const int* in_sizes, int n_in,
                              void* d_out, int out_size, void* d_ws, size_t ws_size,
                              hipStream_t stream) {
  const float* z     = (const float*)d_in[0];
  const int*   inp   = (const int*)d_in[1];
  const float* emb   = (const float*)d_in[2];
  const float* l2h_w = (const float*)d_in[3];
  const float* l2h_b = (const float*)d_in[4];
  const float* wih0  = (const float*)d_in[5];
  const float* whh0  = (const float*)d_in[6];
  const float* bih0  = (const float*)d_in[7];
  const float* bhh0  = (const float*)d_in[8];
  const float* wih1  = (const float*)d_in[9];
  const float* whh1  = (const float*)d_in[10];
  const float* bih1  = (const float*)d_in[11];
  const float* bhh1  = (const float*)d_in[12];
  const float* predw = (const float*)d_in[13];
  const float* predb = (const float*)d_in[14];
  float* out = (float*)d_out;

  char* ws = (char*)d_ws;
  size_t off = 0;
  auto alloc = [&](size_t bytes) {
    char* p = ws + off;
    off = (off + bytes + 255) & ~(size_t)255;
    return p;
  };
  unsigned short* xb     = (unsigned short*)alloc((size_t)BB * SS * EMB * 2);
  unsigned short* wih0b  = (unsigned short*)alloc((size_t)HID * EMB * 2);
  unsigned short* whh0b  = (unsigned short*)alloc((size_t)HID * HID * 2);
  unsigned short* wih1b  = (unsigned short*)alloc((size_t)HID * HID * 2);
  unsigned short* whh1b  = (unsigned short*)alloc((size_t)HID * HID * 2);
  unsigned short* predTb = (unsigned short*)alloc((size_t)VOCAB * HID * 2);
  unsigned short* xw0    = (unsigned short*)alloc((size_t)BB * SS * HID * 2);
  unsigned short* ys0    = (unsigned short*)alloc((size_t)BB * SS * HID * 2);
  unsigned short* ys1    = (unsigned short*)alloc((size_t)BB * SS * HID * 2);
  unsigned short* h0b    = (unsigned short*)alloc((size_t)2 * BB * HID * 2);
  float*          bias0  = (float*)alloc((size_t)HID * 4);
  float*          bias1  = (float*)alloc((size_t)HID * 4);
  unsigned int*   flags  = (unsigned int*)alloc((size_t)2048 * 4);  // flag0[32*16] + flag1[64*16]

  // prep
  k_f2b<<<256, 256, 0, stream>>>(wih0, wih0b, HID * EMB);
  k_f2b<<<256, 256, 0, stream>>>(whh0, whh0b, HID * HID);
  k_f2b<<<256, 256, 0, stream>>>(wih1, wih1b, HID * HID);
  k_f2b<<<256, 256, 0, stream>>>(whh1, whh1b, HID * HID);
  k_misc<<<8, 256, 0, stream>>>(bih0, bhh0, bih1, bhh1, bias0, bias1, flags, 2048);
  k_latent<<<(2 * BB * HID) / 256, 256, 0, stream>>>(z, l2h_w, l2h_b, h0b);
  k_embed<<<BB * SS, 256, 0, stream>>>(emb, inp, xb);
  k_transpose<<<dim3(VOCAB / 32, HID / 32), dim3(32, 8), 0, stream>>>(predw, predTb);

  size_t gemm_lds = (size_t)2 * 128 * 64 * 2;            // 32KB linear
  size_t scan_lds = (size_t)32 * 1032 * 2 + 64 * 4 * 4;  // weights + partial buffer

  // xw0 = x @ w_ih0^T + (b_ih0 + b_hh0)   -> bf16
  gemm_bt<unsigned short><<<(BB * SS / 128) * (HID / 128), 256, gemm_lds, stream>>>(
      xb, wih0b, bias0, xw0, BB * SS, HID, EMB);
  // fused pipelined 2-layer scan (round-5 proven)
  k_scan2<<<96, 128, scan_lds, stream>>>(whh0b, wih1b, whh1b, xw0, bias1, h0b, ys0, ys1, flags);
  // logits = h2 @ pred_w + pred_b  -> fp32 (d_out)
  gemm_bt<float><<<(BB * SS / 128) * (VOCAB / 128), 256, gemm_lds, stream>>>(
      ys1, predTb, predb, out, BB * SS, VOCAB, HID);
}

// Round 12
// 2996.398 us; speedup vs baseline: 1.6686x; 1.0002x over previous
//
#include <hip/hip_runtime.h>
#include <hip/hip_bf16.h>

#define BB 16
#define SS 512
#define VOCAB 32000
#define EMB 512
#define HID 1024
#define LAT 256

typedef __attribute__((ext_vector_type(8))) short bf16x8v;
typedef __attribute__((ext_vector_type(4))) float f32x4v;

__device__ __forceinline__ unsigned short f2b(float f) {
  unsigned int u = __float_as_uint(f);
  unsigned int r = (u + 0x7fffu + ((u >> 16) & 1u)) >> 16;
  return (unsigned short)r;
}

__device__ __forceinline__ float b2f(unsigned short s) {
  return __uint_as_float(((unsigned int)s) << 16);
}

__device__ __forceinline__ float fast_tanh(float x) {
  float t = fminf(fmaxf(x * 2.8853900817779268f, -60.f), 60.f);
  float e = __builtin_amdgcn_exp2f(t);
  return (e - 1.f) * __builtin_amdgcn_rcpf(e + 1.f);
}

// coherent-point 16B load: bypass (possibly stale) L1/L2, read LLC directly.
__device__ __forceinline__ bf16x8v load16_coherent(const unsigned short* p) {
  bf16x8v r;
  asm volatile("global_load_dwordx4 %0, %1, off sc0 sc1"
               : "=v"(r) : "v"(p) : "memory");
  return r;
}

// async global->LDS 16B per lane (lds dest = wave-uniform base + lane*16)
__device__ __forceinline__ void gload_lds16(const unsigned short* g, unsigned short* l) {
  typedef __attribute__((address_space(1))) const unsigned int gu32;
  typedef __attribute__((address_space(3))) unsigned int su32;
  __builtin_amdgcn_global_load_lds((gu32*)g, (su32*)l, 16, 0, 0);
}

// granular vmem wait + scheduling fence (rule #18)
#define WAITV(n)                                                   \
  do {                                                             \
    asm volatile("s_waitcnt vmcnt(" #n ")" ::: "memory");          \
    __builtin_amdgcn_sched_barrier(0);                             \
  } while (0)

// 8-step MFMA chunk: consume HF[K0..K0+8) against LDS weight row WROW into A
#define MCHUNK(HF, WROW, K0, A)                                              \
  _Pragma("unroll")                                                          \
  for (int kk = K0; kk < K0 + 8; ++kk) {                                     \
    bf16x8v bw = *(const bf16x8v*)&Ws[(WROW) * LDW + kk * 32 + fg * 8];      \
    A = __builtin_amdgcn_mfma_f32_16x16x32_bf16(HF[kk], bw, A, 0, 0, 0);     \
  }

// ---------------- generic fp32 -> bf16 ----------------
__global__ __launch_bounds__(256) void k_f2b(const float* __restrict__ src,
                                             unsigned short* __restrict__ dst, int n) {
  int i = blockIdx.x * 256 + threadIdx.x;
  int stride = gridDim.x * 256;
  for (; i < n; i += stride) dst[i] = f2b(src[i]);
}

// ---------------- biases + flag zeroing ----------------
__global__ __launch_bounds__(256) void k_misc(const float* __restrict__ bih0, const float* __restrict__ bhh0,
                                              const float* __restrict__ bih1, const float* __restrict__ bhh1,
                                              float* __restrict__ bias0, float* __restrict__ bias1,
                                              unsigned int* __restrict__ flags, int nflags) {
  int i = blockIdx.x * 256 + threadIdx.x;
  if (i < HID) { bias0[i] = bih0[i] + bhh0[i]; bias1[i] = bih1[i] + bhh1[i]; }
  if (i < nflags) flags[i] = 0u;
}

// ---------------- hidden = z @ l2h_w + b, torch-reshape to [2][16][1024], bf16 ----------------
__global__ __launch_bounds__(256) void k_latent(const float* __restrict__ z, const float* __restrict__ w,
                                                const float* __restrict__ bvec, unsigned short* __restrict__ h0) {
  int idx = blockIdx.x * 256 + threadIdx.x;          // [0, 2*16*1024)
  int l  = idx >> 14;
  int bb = (idx >> 10) & 15;
  int hh = idx & 1023;
  int b = l * 8 + (bb >> 1);                          // torch flat-reshape mapping
  int j = ((bb & 1) << 10) | hh;
  float s = bvec[j];
  for (int k = 0; k < LAT; ++k) s += z[b * LAT + k] * w[k * (HID * 2) + j];
  h0[idx] = f2b(s);
}

// ---------------- embedding gather -> bf16, [b][t][EMB] ----------------
__global__ __launch_bounds__(256) void k_embed(const float* __restrict__ emb, const int* __restrict__ inp,
                                               unsigned short* __restrict__ x) {
  int row = blockIdx.x;                               // B*S
  int tok = inp[row];
  for (int j = threadIdx.x; j < EMB; j += 256)
    x[(long)row * EMB + j] = f2b(emb[(long)tok * EMB + j]);
}

// ---------------- pred_w [K][N] fp32 -> [N][K] bf16 (tiled transpose) ----------------
__global__ void k_transpose(const float* __restrict__ src, unsigned short* __restrict__ dst) {
  __shared__ float tile[32][33];
  int n0 = blockIdx.x * 32;
  int k0 = blockIdx.y * 32;
  int tx = threadIdx.x, ty = threadIdx.y;
  for (int i = ty; i < 32; i += 8)
    tile[i][tx] = src[(long)(k0 + i) * VOCAB + n0 + tx];
  __syncthreads();
  for (int i = ty; i < 32; i += 8)
    dst[(long)(n0 + i) * HID + k0 + tx] = f2b(tile[tx][i]);
}

// ---------------- C[M][N] = A[M][K] * B[N][K]^T + bias[N]  (bf16 in, OUT out) ----------------
// m97-style: 128x128 tile, BK=64, linear LDS [128][64], 16B global_load_lds staging.
template <typename OUT>
__global__ __launch_bounds__(256) void gemm_bt(const unsigned short* __restrict__ A,
                                               const unsigned short* __restrict__ Bm,
                                               const float* __restrict__ bias,
                                               OUT* __restrict__ C,
                                               int M, int N, int K) {
  extern __shared__ unsigned short smem_g[];
  unsigned short* As = smem_g;                         // [128][64] linear
  unsigned short* Bs = smem_g + 128 * 64;              // [128][64] linear

  int nTn = N >> 7;
  int tm = blockIdx.x / nTn, tn = blockIdx.x % nTn;
  long m0 = (long)tm << 7, n0 = (long)tn << 7;
  int t = threadIdx.x;
  int lane = t & 63, w = t >> 6;
  int wr = (w >> 1) * 64, wc = (w & 1) * 64;
  int fr = lane & 15, fg = lane >> 4;

  f32x4v acc[4][4];
  f32x4v zero = {0.f, 0.f, 0.f, 0.f};
#pragma unroll
  for (int i = 0; i < 4; ++i)
#pragma unroll
    for (int j = 0; j < 4; ++j) acc[i][j] = zero;

  const int lrow = lane >> 3;                          // 0..7 within 8-row block
  const int lcol = (lane & 7) * 8;                     // bf16 col within BK=64

  for (int kt = 0; kt < K; kt += 64) {
    // stage A/B tiles: each wave stages rows [w*32, w*32+32) in 4 blocks of 8 rows
#pragma unroll
    for (int c = 0; c < 4; ++c) {
      int rbase = w * 32 + c * 8;
      gload_lds16(&A[(m0 + rbase + lrow) * (long)K + kt + lcol], &As[rbase * 64]);
      gload_lds16(&Bm[(n0 + rbase + lrow) * (long)K + kt + lcol], &Bs[rbase * 64]);
    }
    __syncthreads();
#pragma unroll
    for (int kk = 0; kk < 2; ++kk) {
      int ko = kk * 32 + fg * 8;
      bf16x8v af[4], bfv[4];
#pragma unroll
      for (int i = 0; i < 4; ++i) af[i] = *(const bf16x8v*)&As[(wr + i * 16 + fr) * 64 + ko];
#pragma unroll
      for (int j = 0; j < 4; ++j) bfv[j] = *(const bf16x8v*)&Bs[(wc + j * 16 + fr) * 64 + ko];
#pragma unroll
      for (int i = 0; i < 4; ++i)
#pragma unroll
        for (int j = 0; j < 4; ++j)
          acc[i][j] = __builtin_amdgcn_mfma_f32_16x16x32_bf16(af[i], bfv[j], acc[i][j], 0, 0, 0);
    }
    __syncthreads();
  }

#pragma unroll
  for (int j = 0; j < 4; ++j) {
    long n = n0 + wc + j * 16 + fr;
    float bv = bias[n];
#pragma unroll
    for (int i = 0; i < 4; ++i) {
      long mrow = m0 + wr + i * 16 + fg * 4;
#pragma unroll
      for (int r = 0; r < 4; ++r) {
        float v = acc[i][j][r] + bv;
        if constexpr (__hip_internal::is_same<OUT, float>::value) {
          C[(mrow + r) * (long)N + n] = v;
        } else {
          C[(mrow + r) * (long)N + n] = f2b(v);
        }
      }
    }
  }
}

// ---------------- fused 2-layer pipelined RNN scan (round-5 proven image) ----------------
// 96 WGs x 128 threads (2 waves), persistent. Max 32 in-flight asm loads per wave.
//   WG 0..31  (L0): h1[t] = tanh(xw0[t] + h1[t-1] @ Whh0^T); wave w owns 16 cols.
//   WG 32..95 (L1): h2[t] = tanh(h1[t] @ Wih1^T + h2[t-1] @ Whh1^T + bias1), 16 cols;
//                   wave0 = h1-part (+ epilogue), wave1 = h2-part (partial via LDS).
// Broadcast: relaxed agent-atomic write-through stores; sc0/sc1 bypass loads;
// per-WG flag lines; producer does vmcnt(0) ack before flag store.
__global__ __launch_bounds__(128, 1) void k_scan2(const unsigned short* __restrict__ whh0,
                                                  const unsigned short* __restrict__ wih1,
                                                  const unsigned short* __restrict__ whh1,
                                                  const unsigned short* __restrict__ xw0,   // [B][S][H] bf16 (bias0 folded)
                                                  const float* __restrict__ bias1,
                                                  const unsigned short* __restrict__ h0all, // [2][B][H] bf16
                                                  unsigned short* __restrict__ ys0,         // [B][S][H] bf16
                                                  unsigned short* __restrict__ ys1,         // [B][S][H] bf16
                                                  unsigned int* __restrict__ flags) {       // flag0: [i*16]; flag1: [1024+j*16]
  const int LDW = 1032;                                // pad 8: 2-way bank alias only
  extern __shared__ unsigned short Ws[];
  float* Part = (float*)(Ws + 32 * LDW);               // 64 lanes x f32x4 partial
  const int tid = threadIdx.x;
  const int lane = tid & 63;
  const int wv = tid >> 6;
  const int fr = lane & 15, fg = lane >> 4;
  const int wg = blockIdx.x;
  const f32x4v zero = {0.f, 0.f, 0.f, 0.f};

  if (wg < 32) {
    // ================= Layer 0 =================
    const int nbase = wg * 32;
    for (int c = tid; c < 32 * 128; c += 128) {
      int row = c >> 7, col = (c & 127) << 3;
      *(bf16x8v*)&Ws[row * LDW + col] = *(const bf16x8v*)&whh0[(long)(nbase + row) * HID + col];
    }
    __syncthreads();

    const int wrow = wv * 16 + fr;                     // LDS weight row
    const int mycol = nbase + wrow;                    // output column
    const int odd = fr & 1;

    for (int t = 0; t < SS; ++t) {
      // xw prefetch (independent of h) — overlaps the poll
      unsigned short xv[4];
#pragma unroll
      for (int r = 0; r < 4; ++r)
        xv[r] = xw0[((long)(fg * 4 + r) * SS + t) * HID + mycol];

      if (t > 0) {
        unsigned tgt = (unsigned)t;
        for (;;) {
          unsigned v = 0xffffffffu;
          if (lane < 32)
            v = __hip_atomic_load(&flags[lane << 4], __ATOMIC_RELAXED, __HIP_MEMORY_SCOPE_AGENT);
          if (__all(v >= tgt)) break;
        }
      }
      const unsigned short* hp = (t == 0) ? (h0all + (long)fr * HID)
                                          : (ys0 + ((long)fr * SS + (t - 1)) * HID);
      bf16x8v hf[32];
#pragma unroll
      for (int kk = 0; kk < 32; ++kk) hf[kk] = load16_coherent(&hp[kk * 32 + fg * 8]);
      __builtin_amdgcn_sched_barrier(0);

      f32x4v aA = zero, aB = zero;
      WAITV(24); MCHUNK(hf, wrow, 0,  aA);
      WAITV(16); MCHUNK(hf, wrow, 8,  aB);
      WAITV(8);  MCHUNK(hf, wrow, 16, aA);
      WAITV(0);  MCHUNK(hf, wrow, 24, aB);
      f32x4v acc = aA + aB;

      unsigned av[4], pv[4];
#pragma unroll
      for (int r = 0; r < 4; ++r) {
        av[r] = (unsigned)f2b(fast_tanh(acc[r] + b2f(xv[r])));
        pv[r] = __shfl_xor(av[r], 1);
      }
      if (!odd) {
#pragma unroll
        for (int r = 0; r < 4; ++r)
          __hip_atomic_store((unsigned int*)&ys0[((long)(fg * 4 + r) * SS + t) * HID + mycol],
                             av[r] | (pv[r] << 16), __ATOMIC_RELAXED, __HIP_MEMORY_SCOPE_AGENT);
      }
      WAITV(0);                                        // stores ack'd at coherence point
      __syncthreads();                                 // both waves done
      if (tid == 0)
        __hip_atomic_store(&flags[wg << 4], (unsigned)(t + 1),
                           __ATOMIC_RELAXED, __HIP_MEMORY_SCOPE_AGENT);
    }
  } else {
    // ================= Layer 1 =================
    const int j = wg - 32;
    const int nbase = j * 16;
    for (int c = tid; c < 32 * 128; c += 128) {
      int row = c >> 7, col = (c & 127) << 3;
      const unsigned short* src = (row < 16) ? &wih1[(long)(nbase + row) * HID + col]
                                             : &whh1[(long)(nbase + row - 16) * HID + col];
      *(bf16x8v*)&Ws[row * LDW + col] = *(const bf16x8v*)src;
    }
    __syncthreads();
    const int odd = fr & 1;

    if (wv == 0) {
      // ---- wave0: h1[t] @ Wih1^T + epilogue ----
      const float bv = bias1[nbase + fr];
      for (int t = 0; t < SS; ++t) {
        {
          unsigned tgt = (unsigned)(t + 1);            // L0 finished step t
          for (;;) {
            unsigned v = 0xffffffffu;
            if (lane < 32)
              v = __hip_atomic_load(&flags[lane << 4], __ATOMIC_RELAXED, __HIP_MEMORY_SCOPE_AGENT);
            if (__all(v >= tgt)) break;
          }
        }
        const unsigned short* hp1 = ys0 + ((long)fr * SS + t) * HID;
        bf16x8v hf[32];
#pragma unroll
        for (int kk = 0; kk < 32; ++kk) hf[kk] = load16_coherent(&hp1[kk * 32 + fg * 8]);
        __builtin_amdgcn_sched_barrier(0);

        f32x4v aA = zero, aB = zero;
        WAITV(24); MCHUNK(hf, fr, 0,  aA);
        WAITV(16); MCHUNK(hf, fr, 8,  aB);
        WAITV(8);  MCHUNK(hf, fr, 16, aA);
        WAITV(0);  MCHUNK(hf, fr, 24, aB);

        __syncthreads();                               // wave1's partial is in LDS
        f32x4v part = *(const f32x4v*)&Part[lane << 2];
        f32x4v sum = (aA + aB) + part;

        unsigned av[4], pv[4];
#pragma unroll
        for (int r = 0; r < 4; ++r) {
          av[r] = (unsigned)f2b(fast_tanh(sum[r] + bv));
          pv[r] = __shfl_xor(av[r], 1);
        }
        if (!odd) {
#pragma unroll
          for (int r = 0; r < 4; ++r)
            __hip_atomic_store((unsigned int*)&ys1[((long)(fg * 4 + r) * SS + t) * HID + nbase + fr],
                               av[r] | (pv[r] << 16), __ATOMIC_RELAXED, __HIP_MEMORY_SCOPE_AGENT);
        }
        WAITV(0);                                      // h2 stores ack'd
        if (lane == 0)
          __hip_atomic_store(&flags[1024 + (j << 4)], (unsigned)(t + 1),
                             __ATOMIC_RELAXED, __HIP_MEMORY_SCOPE_AGENT);
      }
    } else {
      // ---- wave1: h2[t-1] @ Whh1^T -> LDS partial ----
      for (int t = 0; t < SS; ++t) {
        if (t > 0) {
          unsigned tgt = (unsigned)t;                  // all L1 WGs finished step t-1
          for (;;) {
            unsigned v = __hip_atomic_load(&flags[1024 + (lane << 4)],
                                           __ATOMIC_RELAXED, __HIP_MEMORY_SCOPE_AGENT);
            if (__all(v >= tgt)) break;
          }
        }
        const unsigned short* hp2 = (t == 0) ? (h0all + (long)(BB + fr) * HID)
                                             : (ys1 + ((long)fr * SS + (t - 1)) * HID);
        bf16x8v hf[32];
#pragma unroll
        for (int kk = 0; kk < 32; ++kk) hf[kk] = load16_coherent(&hp2[kk * 32 + fg * 8]);
        __builtin_amdgcn_sched_barrier(0);

        f32x4v aA = zero, aB = zero;
        WAITV(24); MCHUNK(hf, 16 + fr, 0,  aA);
        WAITV(16); MCHUNK(hf, 16 + fr, 8,  aB);
        WAITV(8);  MCHUNK(hf, 16 + fr, 16, aA);
        WAITV(0);  MCHUNK(hf, 16 + fr, 24, aB);

        *(f32x4v*)&Part[lane << 2] = aA + aB;          // publish partial
        __syncthreads();                               // wave0 consumes after this
      }
    }
  }
}

extern "C" void kernel_launch(void* const* d_in, const int* in_sizes, int n_in,
                              void* d_out, int out_size, void* d_ws, size_t ws_size,
                              hipStream_t stream) {
  const float* z     = (const float*)d_in[0];
  const int*   inp   = (const int*)d_in[1];
  const float* emb   = (const float*)d_in[2];
  const float* l2h_w = (const float*)d_in[3];
  const float* l2h_b = (const float*)d_in[4];
  const float* wih0  = (const float*)d_in[5];
  const float* whh0  = (const float*)d_in[6];
  const float* bih0  = (const float*)d_in[7];
  const float* bhh0  = (const float*)d_in[8];
  const float* wih1  = (const float*)d_in[9];
  const float* whh1  = (const float*)d_in[10];
  const float* bih1  = (const float*)d_in[11];
  const float* bhh1  = (const float*)d_in[12];
  const float* predw = (const float*)d_in[13];
  const float* predb = (const float*)d_in[14];
  float* out = (float*)d_out;

  char* ws = (char*)d_ws;
  size_t off = 0;
  auto alloc = [&](size_t bytes) {
    char* p = ws + off;
    off = (off + bytes + 255) & ~(size_t)255;
    return p;
  };
  unsigned short* xb     = (unsigned short*)alloc((size_t)BB * SS * EMB * 2);
  unsigned short* wih0b  = (unsigned short*)alloc((size_t)HID * EMB * 2);
  unsigned short* whh0b  = (unsigned short*)alloc((size_t)HID * HID * 2);
  unsigned short* wih1b  = (unsigned short*)alloc((size_t)HID * HID * 2);
  unsigned short* whh1b  = (unsigned short*)alloc((size_t)HID * HID * 2);
  unsigned short* predTb = (unsigned short*)alloc((size_t)VOCAB * HID * 2);
  unsigned short* xw0    = (unsigned short*)alloc((size_t)BB * SS * HID * 2);
  unsigned short* ys0    = (unsigned short*)alloc((size_t)BB * SS * HID * 2);
  unsigned short* ys1    = (unsigned short*)alloc((size_t)BB * SS * HID * 2);
  unsigned short* h0b    = (unsigned short*)alloc((size_t)2 * BB * HID * 2);
  float*          bias0  = (float*)alloc((size_t)HID * 4);
  float*          bias1  = (float*)alloc((size_t)HID * 4);
  unsigned int*   flags  = (unsigned int*)alloc((size_t)2048 * 4);  // flag0[32*16] + flag1[64*16]

  // prep
  k_f2b<<<256, 256, 0, stream>>>(wih0, wih0b, HID * EMB);
  k_f2b<<<256, 256, 0, stream>>>(whh0, whh0b, HID * HID);
  k_f2b<<<256, 256, 0, stream>>>(wih1, wih1b, HID * HID);
  k_f2b<<<256, 256, 0, stream>>>(whh1, whh1b, HID * HID);
  k_misc<<<8, 256, 0, stream>>>(bih0, bhh0, bih1, bhh1, bias0, bias1, flags, 2048);
  k_latent<<<(2 * BB * HID) / 256, 256, 0, stream>>>(z, l2h_w, l2h_b, h0b);
  k_embed<<<BB * SS, 256, 0, stream>>>(emb, inp, xb);
  k_transpose<<<dim3(VOCAB / 32, HID / 32), dim3(32, 8), 0, stream>>>(predw, predTb);

  size_t gemm_lds = (size_t)2 * 128 * 64 * 2;            // 32KB linear
  size_t scan_lds = (size_t)32 * 1032 * 2 + 64 * 4 * 4;  // weights + partial buffer

  // xw0 = x @ w_ih0^T + (b_ih0 + b_hh0)   -> bf16
  gemm_bt<unsigned short><<<(BB * SS / 128) * (HID / 128), 256, gemm_lds, stream>>>(
      xb, wih0b, bias0, xw0, BB * SS, HID, EMB);
  // fused pipelined 2-layer scan (round-5 proven)
  k_scan2<<<96, 128, scan_lds, stream>>>(whh0b, wih1b, whh1b, xw0, bias1, h0b, ys0, ys1, flags);
  // logits = h2 @ pred_w + pred_b  -> fp32 (d_out)
  gemm_bt<float><<<(BB * SS / 128) * (VOCAB / 128), 256, gemm_lds, stream>>>(
      ys1, predTb, predb, out, BB * SS, VOCAB, HID);
}

// Round 13
// 2996.198 us; speedup vs baseline: 1.6687x; 1.0001x over previous
//
#include <hip/hip_runtime.h>
#include <hip/hip_bf16.h>

#define BB 16
#define SS 512
#define VOCAB 32000
#define EMB 512
#define HID 1024
#define LAT 256

typedef __attribute__((ext_vector_type(8))) short bf16x8v;
typedef __attribute__((ext_vector_type(4))) float f32x4v;

__device__ __forceinline__ unsigned short f2b(float f) {
  unsigned int u = __float_as_uint(f);
  unsigned int r = (u + 0x7fffu + ((u >> 16) & 1u)) >> 16;
  return (unsigned short)r;
}

__device__ __forceinline__ float b2f(unsigned short s) {
  return __uint_as_float(((unsigned int)s) << 16);
}

__device__ __forceinline__ float fast_tanh(float x) {
  float t = fminf(fmaxf(x * 2.8853900817779268f, -60.f), 60.f);
  float e = __builtin_amdgcn_exp2f(t);
  return (e - 1.f) * __builtin_amdgcn_rcpf(e + 1.f);
}

// coherent-point 16B load: bypass (possibly stale) L1/L2, read LLC directly.
__device__ __forceinline__ bf16x8v load16_coherent(const unsigned short* p) {
  bf16x8v r;
  asm volatile("global_load_dwordx4 %0, %1, off sc0 sc1"
               : "=v"(r) : "v"(p) : "memory");
  return r;
}

// async global->LDS 16B per lane (lds dest = wave-uniform base + lane*16)
__device__ __forceinline__ void gload_lds16(const unsigned short* g, unsigned short* l) {
  typedef __attribute__((address_space(1))) const unsigned int gu32;
  typedef __attribute__((address_space(3))) unsigned int su32;
  __builtin_amdgcn_global_load_lds((gu32*)g, (su32*)l, 16, 0, 0);
}

// granular vmem wait + scheduling fence (rule #18)
#define WAITV(n)                                                   \
  do {                                                             \
    asm volatile("s_waitcnt vmcnt(" #n ")" ::: "memory");          \
    __builtin_amdgcn_sched_barrier(0);                             \
  } while (0)

// 8-step MFMA chunk: consume HF[K0..K0+8) against LDS weight row WROW into A
#define MCHUNK(HF, WROW, K0, A)                                              \
  _Pragma("unroll")                                                          \
  for (int kk = K0; kk < K0 + 8; ++kk) {                                     \
    bf16x8v bw = *(const bf16x8v*)&Ws[(WROW) * LDW + kk * 32 + fg * 8];      \
    A = __builtin_amdgcn_mfma_f32_16x16x32_bf16(HF[kk], bw, A, 0, 0, 0);     \
  }

// ---------------- generic fp32 -> bf16 ----------------
__global__ __launch_bounds__(256) void k_f2b(const float* __restrict__ src,
                                             unsigned short* __restrict__ dst, int n) {
  int i = blockIdx.x * 256 + threadIdx.x;
  int stride = gridDim.x * 256;
  for (; i < n; i += stride) dst[i] = f2b(src[i]);
}

// ---------------- biases + flag zeroing ----------------
__global__ __launch_bounds__(256) void k_misc(const float* __restrict__ bih0, const float* __restrict__ bhh0,
                                              const float* __restrict__ bih1, const float* __restrict__ bhh1,
                                              float* __restrict__ bias0, float* __restrict__ bias1,
                                              unsigned int* __restrict__ flags, int nflags) {
  int i = blockIdx.x * 256 + threadIdx.x;
  if (i < HID) { bias0[i] = bih0[i] + bhh0[i]; bias1[i] = bih1[i] + bhh1[i]; }
  if (i < nflags) flags[i] = 0u;
}

// ---------------- hidden = z @ l2h_w + b, torch-reshape to [2][16][1024], bf16 ----------------
__global__ __launch_bounds__(256) void k_latent(const float* __restrict__ z, const float* __restrict__ w,
                                                const float* __restrict__ bvec, unsigned short* __restrict__ h0) {
  int idx = blockIdx.x * 256 + threadIdx.x;          // [0, 2*16*1024)
  int l  = idx >> 14;
  int bb = (idx >> 10) & 15;
  int hh = idx & 1023;
  int b = l * 8 + (bb >> 1);                          // torch flat-reshape mapping
  int j = ((bb & 1) << 10) | hh;
  float s = bvec[j];
  for (int k = 0; k < LAT; ++k) s += z[b * LAT + k] * w[k * (HID * 2) + j];
  h0[idx] = f2b(s);
}

// ---------------- embedding gather -> bf16, [b][t][EMB] ----------------
__global__ __launch_bounds__(256) void k_embed(const float* __restrict__ emb, const int* __restrict__ inp,
                                               unsigned short* __restrict__ x) {
  int row = blockIdx.x;                               // B*S
  int tok = inp[row];
  for (int j = threadIdx.x; j < EMB; j += 256)
    x[(long)row * EMB + j] = f2b(emb[(long)tok * EMB + j]);
}

// ---------------- pred_w [K][N] fp32 -> [N][K] bf16 (tiled transpose) ----------------
__global__ void k_transpose(const float* __restrict__ src, unsigned short* __restrict__ dst) {
  __shared__ float tile[32][33];
  int n0 = blockIdx.x * 32;
  int k0 = blockIdx.y * 32;
  int tx = threadIdx.x, ty = threadIdx.y;
  for (int i = ty; i < 32; i += 8)
    tile[i][tx] = src[(long)(k0 + i) * VOCAB + n0 + tx];
  __syncthreads();
  for (int i = ty; i < 32; i += 8)
    dst[(long)(n0 + i) * HID + k0 + tx] = f2b(tile[tx][i]);
}

// ---------------- C[M][N] = A[M][K] * B[N][K]^T + bias[N]  (bf16 in, OUT out) ----------------
// m97-style: 128x128 tile, BK=64, linear LDS [128][64], 16B global_load_lds staging.
template <typename OUT>
__global__ __launch_bounds__(256) void gemm_bt(const unsigned short* __restrict__ A,
                                               const unsigned short* __restrict__ Bm,
                                               const float* __restrict__ bias,
                                               OUT* __restrict__ C,
                                               int M, int N, int K) {
  extern __shared__ unsigned short smem_g[];
  unsigned short* As = smem_g;                         // [128][64] linear
  unsigned short* Bs = smem_g + 128 * 64;              // [128][64] linear

  int nTn = N >> 7;
  int tm = blockIdx.x / nTn, tn = blockIdx.x % nTn;
  long m0 = (long)tm << 7, n0 = (long)tn << 7;
  int t = threadIdx.x;
  int lane = t & 63, w = t >> 6;
  int wr = (w >> 1) * 64, wc = (w & 1) * 64;
  int fr = lane & 15, fg = lane >> 4;

  f32x4v acc[4][4];
  f32x4v zero = {0.f, 0.f, 0.f, 0.f};
#pragma unroll
  for (int i = 0; i < 4; ++i)
#pragma unroll
    for (int j = 0; j < 4; ++j) acc[i][j] = zero;

  const int lrow = lane >> 3;                          // 0..7 within 8-row block
  const int lcol = (lane & 7) * 8;                     // bf16 col within BK=64

  for (int kt = 0; kt < K; kt += 64) {
    // stage A/B tiles: each wave stages rows [w*32, w*32+32) in 4 blocks of 8 rows
#pragma unroll
    for (int c = 0; c < 4; ++c) {
      int rbase = w * 32 + c * 8;
      gload_lds16(&A[(m0 + rbase + lrow) * (long)K + kt + lcol], &As[rbase * 64]);
      gload_lds16(&Bm[(n0 + rbase + lrow) * (long)K + kt + lcol], &Bs[rbase * 64]);
    }
    __syncthreads();
#pragma unroll
    for (int kk = 0; kk < 2; ++kk) {
      int ko = kk * 32 + fg * 8;
      bf16x8v af[4], bfv[4];
#pragma unroll
      for (int i = 0; i < 4; ++i) af[i] = *(const bf16x8v*)&As[(wr + i * 16 + fr) * 64 + ko];
#pragma unroll
      for (int j = 0; j < 4; ++j) bfv[j] = *(const bf16x8v*)&Bs[(wc + j * 16 + fr) * 64 + ko];
#pragma unroll
      for (int i = 0; i < 4; ++i)
#pragma unroll
        for (int j = 0; j < 4; ++j)
          acc[i][j] = __builtin_amdgcn_mfma_f32_16x16x32_bf16(af[i], bfv[j], acc[i][j], 0, 0, 0);
    }
    __syncthreads();
  }

#pragma unroll
  for (int j = 0; j < 4; ++j) {
    long n = n0 + wc + j * 16 + fr;
    float bv = bias[n];
#pragma unroll
    for (int i = 0; i < 4; ++i) {
      long mrow = m0 + wr + i * 16 + fg * 4;
#pragma unroll
      for (int r = 0; r < 4; ++r) {
        float v = acc[i][j][r] + bv;
        if constexpr (__hip_internal::is_same<OUT, float>::value) {
          C[(mrow + r) * (long)N + n] = v;
        } else {
          C[(mrow + r) * (long)N + n] = f2b(v);
        }
      }
    }
  }
}

// ---------------- fused 2-layer pipelined RNN scan (round-5 proven image) ----------------
// 96 WGs x 128 threads (2 waves), persistent. Max 32 in-flight asm loads per wave.
//   WG 0..31  (L0): h1[t] = tanh(xw0[t] + h1[t-1] @ Whh0^T); wave w owns 16 cols.
//   WG 32..95 (L1): h2[t] = tanh(h1[t] @ Wih1^T + h2[t-1] @ Whh1^T + bias1), 16 cols;
//                   wave0 = h1-part (+ epilogue), wave1 = h2-part (partial via LDS).
// Broadcast: relaxed agent-atomic write-through stores; sc0/sc1 bypass loads;
// per-WG flag lines; producer does vmcnt(0) ack before flag store.
__global__ __launch_bounds__(128, 1) void k_scan2(const unsigned short* __restrict__ whh0,
                                                  const unsigned short* __restrict__ wih1,
                                                  const unsigned short* __restrict__ whh1,
                                                  const unsigned short* __restrict__ xw0,   // [B][S][H] bf16 (bias0 folded)
                                                  const float* __restrict__ bias1,
                                                  const unsigned short* __restrict__ h0all, // [2][B][H] bf16
                                                  unsigned short* __restrict__ ys0,         // [B][S][H] bf16
                                                  unsigned short* __restrict__ ys1,         // [B][S][H] bf16
                                                  unsigned int* __restrict__ flags) {       // flag0: [i*16]; flag1: [1024+j*16]
  const int LDW = 1032;                                // pad 8: 2-way bank alias only
  extern __shared__ unsigned short Ws[];
  float* Part = (float*)(Ws + 32 * LDW);               // 64 lanes x f32x4 partial
  const int tid = threadIdx.x;
  const int lane = tid & 63;
  const int wv = tid >> 6;
  const int fr = lane & 15, fg = lane >> 4;
  const int wg = blockIdx.x;
  const f32x4v zero = {0.f, 0.f, 0.f, 0.f};

  if (wg < 32) {
    // ================= Layer 0 =================
    const int nbase = wg * 32;
    for (int c = tid; c < 32 * 128; c += 128) {
      int row = c >> 7, col = (c & 127) << 3;
      *(bf16x8v*)&Ws[row * LDW + col] = *(const bf16x8v*)&whh0[(long)(nbase + row) * HID + col];
    }
    __syncthreads();

    const int wrow = wv * 16 + fr;                     // LDS weight row
    const int mycol = nbase + wrow;                    // output column
    const int odd = fr & 1;

    for (int t = 0; t < SS; ++t) {
      // xw prefetch (independent of h) — overlaps the poll
      unsigned short xv[4];
#pragma unroll
      for (int r = 0; r < 4; ++r)
        xv[r] = xw0[((long)(fg * 4 + r) * SS + t) * HID + mycol];

      if (t > 0) {
        unsigned tgt = (unsigned)t;
        for (;;) {
          unsigned v = 0xffffffffu;
          if (lane < 32)
            v = __hip_atomic_load(&flags[lane << 4], __ATOMIC_RELAXED, __HIP_MEMORY_SCOPE_AGENT);
          if (__all(v >= tgt)) break;
        }
      }
      const unsigned short* hp = (t == 0) ? (h0all + (long)fr * HID)
                                          : (ys0 + ((long)fr * SS + (t - 1)) * HID);
      bf16x8v hf[32];
#pragma unroll
      for (int kk = 0; kk < 32; ++kk) hf[kk] = load16_coherent(&hp[kk * 32 + fg * 8]);
      __builtin_amdgcn_sched_barrier(0);

      f32x4v aA = zero, aB = zero;
      WAITV(24); MCHUNK(hf, wrow, 0,  aA);
      WAITV(16); MCHUNK(hf, wrow, 8,  aB);
      WAITV(8);  MCHUNK(hf, wrow, 16, aA);
      WAITV(0);  MCHUNK(hf, wrow, 24, aB);
      f32x4v acc = aA + aB;

      unsigned av[4], pv[4];
#pragma unroll
      for (int r = 0; r < 4; ++r) {
        av[r] = (unsigned)f2b(fast_tanh(acc[r] + b2f(xv[r])));
        pv[r] = __shfl_xor(av[r], 1);
      }
      if (!odd) {
#pragma unroll
        for (int r = 0; r < 4; ++r)
          __hip_atomic_store((unsigned int*)&ys0[((long)(fg * 4 + r) * SS + t) * HID + mycol],
                             av[r] | (pv[r] << 16), __ATOMIC_RELAXED, __HIP_MEMORY_SCOPE_AGENT);
      }
      WAITV(0);                                        // stores ack'd at coherence point
      __syncthreads();                                 // both waves done
      if (tid == 0)
        __hip_atomic_store(&flags[wg << 4], (unsigned)(t + 1),
                           __ATOMIC_RELAXED, __HIP_MEMORY_SCOPE_AGENT);
    }
  } else {
    // ================= Layer 1 =================
    const int j = wg - 32;
    const int nbase = j * 16;
    for (int c = tid; c < 32 * 128; c += 128) {
      int row = c >> 7, col = (c & 127) << 3;
      const unsigned short* src = (row < 16) ? &wih1[(long)(nbase + row) * HID + col]
                                             : &whh1[(long)(nbase + row - 16) * HID + col];
      *(bf16x8v*)&Ws[row * LDW + col] = *(const bf16x8v*)src;
    }
    __syncthreads();
    const int odd = fr & 1;

    if (wv == 0) {
      // ---- wave0: h1[t] @ Wih1^T + epilogue ----
      const float bv = bias1[nbase + fr];
      for (int t = 0; t < SS; ++t) {
        {
          unsigned tgt = (unsigned)(t + 1);            // L0 finished step t
          for (;;) {
            unsigned v = 0xffffffffu;
            if (lane < 32)
              v = __hip_atomic_load(&flags[lane << 4], __ATOMIC_RELAXED, __HIP_MEMORY_SCOPE_AGENT);
            if (__all(v >= tgt)) break;
          }
        }
        const unsigned short* hp1 = ys0 + ((long)fr * SS + t) * HID;
        bf16x8v hf[32];
#pragma unroll
        for (int kk = 0; kk < 32; ++kk) hf[kk] = load16_coherent(&hp1[kk * 32 + fg * 8]);
        __builtin_amdgcn_sched_barrier(0);

        f32x4v aA = zero, aB = zero;
        WAITV(24); MCHUNK(hf, fr, 0,  aA);
        WAITV(16); MCHUNK(hf, fr, 8,  aB);
        WAITV(8);  MCHUNK(hf, fr, 16, aA);
        WAITV(0);  MCHUNK(hf, fr, 24, aB);

        __syncthreads();                               // wave1's partial is in LDS
        f32x4v part = *(const f32x4v*)&Part[lane << 2];
        f32x4v sum = (aA + aB) + part;

        unsigned av[4], pv[4];
#pragma unroll
        for (int r = 0; r < 4; ++r) {
          av[r] = (unsigned)f2b(fast_tanh(sum[r] + bv));
          pv[r] = __shfl_xor(av[r], 1);
        }
        if (!odd) {
#pragma unroll
          for (int r = 0; r < 4; ++r)
            __hip_atomic_store((unsigned int*)&ys1[((long)(fg * 4 + r) * SS + t) * HID + nbase + fr],
                               av[r] | (pv[r] << 16), __ATOMIC_RELAXED, __HIP_MEMORY_SCOPE_AGENT);
        }
        WAITV(0);                                      // h2 stores ack'd
        if (lane == 0)
          __hip_atomic_store(&flags[1024 + (j << 4)], (unsigned)(t + 1),
                             __ATOMIC_RELAXED, __HIP_MEMORY_SCOPE_AGENT);
      }
    } else {
      // ---- wave1: h2[t-1] @ Whh1^T -> LDS partial ----
      for (int t = 0; t < SS; ++t) {
        if (t > 0) {
          unsigned tgt = (unsigned)t;                  // all L1 WGs finished step t-1
          for (;;) {
            unsigned v = __hip_atomic_load(&flags[1024 + (lane << 4)],
                                           __ATOMIC_RELAXED, __HIP_MEMORY_SCOPE_AGENT);
            if (__all(v >= tgt)) break;
          }
        }
        const unsigned short* hp2 = (t == 0) ? (h0all + (long)(BB + fr) * HID)
                                             : (ys1 + ((long)fr * SS + (t - 1)) * HID);
        bf16x8v hf[32];
#pragma unroll
        for (int kk = 0; kk < 32; ++kk) hf[kk] = load16_coherent(&hp2[kk * 32 + fg * 8]);
        __builtin_amdgcn_sched_barrier(0);

        f32x4v aA = zero, aB = zero;
        WAITV(24); MCHUNK(hf, 16 + fr, 0,  aA);
        WAITV(16); MCHUNK(hf, 16 + fr, 8,  aB);
        WAITV(8);  MCHUNK(hf, 16 + fr, 16, aA);
        WAITV(0);  MCHUNK(hf, 16 + fr, 24, aB);

        *(f32x4v*)&Part[lane << 2] = aA + aB;          // publish partial
        __syncthreads();                               // wave0 consumes after this
      }
    }
  }
}

extern "C" void kernel_launch(void* const* d_in, const int* in_sizes, int n_in,
                              void* d_out, int out_size, void* d_ws, size_t ws_size,
                              hipStream_t stream) {
  const float* z     = (const float*)d_in[0];
  const int*   inp   = (const int*)d_in[1];
  const float* emb   = (const float*)d_in[2];
  const float* l2h_w = (const float*)d_in[3];
  const float* l2h_b = (const float*)d_in[4];
  const float* wih0  = (const float*)d_in[5];
  const float* whh0  = (const float*)d_in[6];
  const float* bih0  = (const float*)d_in[7];
  const float* bhh0  = (const float*)d_in[8];
  const float* wih1  = (const float*)d_in[9];
  const float* whh1  = (const float*)d_in[10];
  const float* bih1  = (const float*)d_in[11];
  const float* bhh1  = (const float*)d_in[12];
  const float* predw = (const float*)d_in[13];
  const float* predb = (const float*)d_in[14];
  float* out = (float*)d_out;

  char* ws = (char*)d_ws;
  size_t off = 0;
  auto alloc = [&](size_t bytes) {
    char* p = ws + off;
    off = (off + bytes + 255) & ~(size_t)255;
    return p;
  };
  unsigned short* xb     = (unsigned short*)alloc((size_t)BB * SS * EMB * 2);
  unsigned short* wih0b  = (unsigned short*)alloc((size_t)HID * EMB * 2);
  unsigned short* whh0b  = (unsigned short*)alloc((size_t)HID * HID * 2);
  unsigned short* wih1b  = (unsigned short*)alloc((size_t)HID * HID * 2);
  unsigned short* whh1b  = (unsigned short*)alloc((size_t)HID * HID * 2);
  unsigned short* predTb = (unsigned short*)alloc((size_t)VOCAB * HID * 2);
  unsigned short* xw0    = (unsigned short*)alloc((size_t)BB * SS * HID * 2);
  unsigned short* ys0    = (unsigned short*)alloc((size_t)BB * SS * HID * 2);
  unsigned short* ys1    = (unsigned short*)alloc((size_t)BB * SS * HID * 2);
  unsigned short* h0b    = (unsigned short*)alloc((size_t)2 * BB * HID * 2);
  float*          bias0  = (float*)alloc((size_t)HID * 4);
  float*          bias1  = (float*)alloc((size_t)HID * 4);
  unsigned int*   flags  = (unsigned int*)alloc((size_t)2048 * 4);  // flag0[32*16] + flag1[64*16]

  // prep
  k_f2b<<<256, 256, 0, stream>>>(wih0, wih0b, HID * EMB);
  k_f2b<<<256, 256, 0, stream>>>(whh0, whh0b, HID * HID);
  k_f2b<<<256, 256, 0, stream>>>(wih1, wih1b, HID * HID);
  k_f2b<<<256, 256, 0, stream>>>(whh1, whh1b, HID * HID);
  k_misc<<<8, 256, 0, stream>>>(bih0, bhh0, bih1, bhh1, bias0, bias1, flags, 2048);
  k_latent<<<(2 * BB * HID) / 256, 256, 0, stream>>>(z, l2h_w, l2h_b, h0b);
  k_embed<<<BB * SS, 256, 0, stream>>>(emb, inp, xb);
  k_transpose<<<dim3(VOCAB / 32, HID / 32), dim3(32, 8), 0, stream>>>(predw, predTb);

  size_t gemm_lds = (size_t)2 * 128 * 64 * 2;            // 32KB linear
  size_t scan_lds = (size_t)32 * 1032 * 2 + 64 * 4 * 4;  // weights + partial buffer

  // xw0 = x @ w_ih0^T + (b_ih0 + b_hh0)   -> bf16
  gemm_bt<unsigned short><<<(BB * SS / 128) * (HID / 128), 256, gemm_lds, stream>>>(
      xb, wih0b, bias0, xw0, BB * SS, HID, EMB);
  // fused pipelined 2-layer scan (round-5 proven)
  k_scan2<<<96, 128, scan_lds, stream>>>(whh0b, wih1b, whh1b, xw0, bias1, h0b, ys0, ys1, flags);
  // logits = h2 @ pred_w + pred_b  -> fp32 (d_out)
  gemm_bt<float><<<(BB * SS / 128) * (VOCAB / 128), 256, gemm_lds, stream>>>(
      ys1, predTb, predb, out, BB * SS, VOCAB, HID);
}